// Round 5
// baseline (121.870 us; speedup 1.0000x reference)
//
#include <hip/hip_runtime.h>

// DIN encoder. B=8, N=512, D=64, H=64. Two launches:
//   prep   — weight transforms, hq, hk-scatter, X B-frags, enc-X B-frags
//   k2_main— ONE BLOCK PER (b,q); 4 waves split key chunks (c += 4);
//            LDS-reduce partial encoded at the end. 32 keys/iter via MFMA.
// R4 lesson: (256,4) → 64-VGPR cap → 200MB scratch spill. Keep (256,2).
// R5 lesson target: occupancy 11.6% was the binder — 1024 blocks, 16-iter
// waves. Now 4096 blocks, ≤4 iters/wave.
#define NB 8
#define NN 512

// ws layout (float offsets)
#define WS_WMF 0        // Wm A-frag-major fp32 [8 slot][64 lane][8]          4096
#define WS_HQ  4096     // hq fp32 [B*N][64]                                262144
#define WS_BF  266240   // B-frags bf16 [B][32 t][4 c][64 lane][8]   (262144 fl)
#define WS_XE  528384   // enc-X bf16 [B][16 c32][4 nt][64 lane][8]  (131072 fl)
// total 659456 floats = 2.64 MB

typedef float fx4 __attribute__((ext_vector_type(4)));
typedef short sx8 __attribute__((ext_vector_type(8)));
typedef int   ix4 __attribute__((ext_vector_type(4)));

static __device__ inline unsigned short f2bf(float f) {
    unsigned u = __float_as_uint(f);
    return (unsigned short)((u + 0x7FFFu + ((u >> 16) & 1u)) >> 16);  // RNE
}

// ---------------- fused prep ----------------
__global__ __launch_bounds__(256) void prep(const float* __restrict__ x,
                                            const float* __restrict__ vm,
                                            const float* __restrict__ W1,
                                            const float* __restrict__ b1,
                                            float* __restrict__ ws) {
    __shared__ float lwq[64 * 65];   // (Wq+Wd)^T  [d][h], pad 65
    __shared__ float lwk[64 * 65];   // (Wk-Wd)^T
    __shared__ float xs[256];
    const int t = threadIdx.x;
    const int blk = blockIdx.x;

    // stage weight combos, coalesced over d
    {
        int d = t & 63, hb = t >> 6;
        #pragma unroll 4
        for (int i = 0; i < 16; ++i) {
            int h = i * 4 + hb;
            float a = W1[h * 256 + d];
            float bb = W1[h * 256 + 64 + d];
            float c = W1[h * 256 + 128 + d];
            lwq[d * 65 + h] = a + c;
            lwk[d * 65 + h] = bb - c;
        }
    }
    const int r0 = blk * 4;
    xs[t] = x[r0 * 64 + t];
    __syncthreads();

    // hq + hk for this block's 4 rows
    {
        int r = t >> 6, h = t & 63;
        const float* xr = xs + r * 64;
        float aq = b1[h], ak = 0.f;
        #pragma unroll
        for (int dd = 0; dd < 64; ++dd) {
            float xv = xr[dd];
            aq = fmaf(xv, lwq[dd * 65 + h], aq);
            ak = fmaf(xv, lwk[dd * 65 + h], ak);
        }
        int row = r0 + r;
        (ws + WS_HQ)[row * 64 + h] = aq;
        // scatter hk into B-frag chunk c=2+(h>>5)
        unsigned short* bfp = (unsigned short*)(ws + WS_BF);
        int bb = row >> 9, k = row & 511;
        int tt = k >> 4, nn = k & 15;
        int c = 2 + (h >> 5);
        int qd = (h >> 3) & 3, j = h & 7;
        int ln = qd * 16 + nn;
        bfp[((((bb * 32 + tt) * 4 + c) * 64 + ln) << 3) + j] = f2bf(ak);
    }

    if (blk < 256) {
        int b = blk >> 5, t5 = blk & 31;
        // X -> BF chunks 0/1
        if (t < 128) {
            unsigned short* bfp = (unsigned short*)(ws + WS_BF);
            int c = t >> 6, L = t & 63;
            int nn = L & 15, qd = L >> 4;
            const float* src = x + ((b * 512 + t5 * 16 + nn) * 64 + c * 32 + qd * 8);
            fx4 v0 = *(const fx4*)src;
            fx4 v1 = *(const fx4*)(src + 4);
            uint4 o;
            o.x = (unsigned)f2bf(v0[0]) | ((unsigned)f2bf(v0[1]) << 16);
            o.y = (unsigned)f2bf(v0[2]) | ((unsigned)f2bf(v0[3]) << 16);
            o.z = (unsigned)f2bf(v1[0]) | ((unsigned)f2bf(v1[1]) << 16);
            o.w = (unsigned)f2bf(v1[2]) | ((unsigned)f2bf(v1[3]) << 16);
            *(uint4*)(bfp + ((((b * 32 + t5) * 4 + c) * 64 + L) << 3)) = o;
        }
        // masked X -> enc B-frags (XE)
        {
            unsigned short* xep = (unsigned short*)(ws + WS_XE);
            int c32 = t5 >> 1, half = t5 & 1;
            int nt = t >> 6, r = t & 63;
            int L = half * 32 + (r & 31);
            int j0 = (r >> 5) * 4;
            int quad = L >> 4, nn = L & 15;
            unsigned short u[4];
            #pragma unroll
            for (int i = 0; i < 4; ++i) {
                int key = c32 * 32 + quad * 8 + j0 + i;
                float v = x[(b * 512 + key) * 64 + nt * 16 + nn] * vm[b * 512 + key];
                u[i] = f2bf(v);
            }
            uint2 o;
            o.x = (unsigned)u[0] | ((unsigned)u[1] << 16);
            o.y = (unsigned)u[2] | ((unsigned)u[3] << 16);
            *(uint2*)(xep + (((((b * 16 + c32) * 4 + nt) * 64 + L) << 3) + j0)) = o;
        }
    } else if (blk < 258) {
        // Wm A-fragment-major
        float* wmf = ws + WS_WMF;
        int e = (blk - 256) * 256 + t;       // 0..511
        int slot = e >> 6, lane = e & 63;
        int ht = slot >> 1, hf = slot & 1;
        int m = lane & 15, qd = lane >> 4;
        int h = ht * 16 + m;
        int dbase = hf * 32 + qd * 8;
        #pragma unroll
        for (int j = 0; j < 8; ++j)
            wmf[e * 8 + j] = W1[h * 256 + 192 + dbase + j];
    }
}

// ---------------- main: one BLOCK per (b,q), 4 waves split chunks ----------------
__global__ __launch_bounds__(256, 2) void k2_main(const float* __restrict__ x,
                                                  const float* __restrict__ prelu_a,
                                                  const float* __restrict__ W2,
                                                  const float* __restrict__ b2,
                                                  const float* __restrict__ ws,
                                                  float* __restrict__ out) {
    const int tid  = threadIdx.x;
    const int lane = tid & 63;
    const int w    = tid >> 6;          // wave id within block: chunk offset
    const int bq   = blockIdx.x;
    const int b    = bq >> 9;
    const int q    = bq & 511;
    const int n    = lane & 15, quad = lane >> 4;

    const float* wmf = ws + WS_WMF;
    const float* hq  = ws + WS_HQ;
    const unsigned short* bfp = (const unsigned short*)(ws + WS_BF);
    const unsigned short* xep = (const unsigned short*)(ws + WS_XE);

    const float pa  = prelu_a[0];
    const float b2v = b2[0];

    __shared__ float red[256];

    // hq (acc init) and W2 registers: h = ht*16 + quad*4 + r
    float hqr[4][4], w2r[4][4];
    #pragma unroll
    for (int ht = 0; ht < 4; ++ht) {
        fx4 vh = *(const fx4*)(hq + bq * 64 + ht * 16 + quad * 4);
        fx4 vw = *(const fx4*)(W2 + ht * 16 + quad * 4);
        #pragma unroll
        for (int r = 0; r < 4; ++r) { hqr[ht][r] = vh[r]; w2r[ht][r] = vw[r]; }
    }

    // xq for A-frags: lane needs d = half*32 + quad*8 + j
    float xq[2][8];
    {
        const float* xp = x + bq * 64 + quad * 8;
        fx4 t0 = *(const fx4*)xp;
        fx4 t1 = *(const fx4*)(xp + 4);
        fx4 t2 = *(const fx4*)(xp + 32);
        fx4 t3 = *(const fx4*)(xp + 36);
        #pragma unroll
        for (int j = 0; j < 4; ++j) {
            xq[0][j] = t0[j]; xq[0][4 + j] = t1[j];
            xq[1][j] = t2[j]; xq[1][4 + j] = t3[j];
        }
    }

    // A-frags: Wm ⊙ xq (bf16)
    sx8 afrag[4][2];
    #pragma unroll
    for (int ht = 0; ht < 4; ++ht)
        #pragma unroll
        for (int hf = 0; hf < 2; ++hf) {
            const float* wp = wmf + (((ht * 2 + hf) * 64 + lane) << 3);
            fx4 w0 = *(const fx4*)wp;
            fx4 w1 = *(const fx4*)(wp + 4);
            sx8 a;
            #pragma unroll
            for (int j = 0; j < 4; ++j) {
                a[j]     = (short)f2bf(w0[j] * xq[hf][j]);
                a[4 + j] = (short)f2bf(w1[j] * xq[hf][4 + j]);
            }
            afrag[ht][hf] = a;
        }

    // one-hot A-frags for the hk fold
    sx8 oh[4];
    #pragma unroll
    for (int ht = 0; ht < 4; ++ht) {
        sx8 a;
        #pragma unroll
        for (int j = 0; j < 8; ++j) {
            int hp = (ht >> 1) * 32 + quad * 8 + j;
            a[j] = (hp == ht * 16 + n) ? (short)0x3F80 : (short)0;
        }
        oh[ht] = a;
    }

    // score -> A-frag gather constants
    int idxs[8];
    #pragma unroll
    for (int j = 0; j < 8; ++j) idxs[j] = ((quad * 8 + j) & 15) << 2;
    const unsigned sel = (quad < 2) ? 0x05040100u : 0x07060302u;

    fx4 eacc[4];
    #pragma unroll
    for (int nt = 0; nt < 4; ++nt) eacc[nt] = (fx4){0.f, 0.f, 0.f, 0.f};

    const int cmax = q >> 5;
    for (int c = w; c <= cmax; c += 4) {
        const unsigned short* fb = bfp + ((((b * 32 + 2 * c) * 4) * 64 + lane) << 3);
        sx8 fa0 = *(const sx8*)(fb);
        sx8 fa1 = *(const sx8*)(fb + 512);
        sx8 fa2 = *(const sx8*)(fb + 1024);
        sx8 fa3 = *(const sx8*)(fb + 1536);
        sx8 fb0 = *(const sx8*)(fb + 2048);
        sx8 fb1 = *(const sx8*)(fb + 2560);
        sx8 fb2 = *(const sx8*)(fb + 3072);
        sx8 fb3 = *(const sx8*)(fb + 3584);
        const unsigned short* fe = xep + ((((b * 16 + c) * 4) * 64 + lane) << 3);
        sx8 e0 = *(const sx8*)(fe);
        sx8 e1 = *(const sx8*)(fe + 512);
        sx8 e2 = *(const sx8*)(fe + 1024);
        sx8 e3 = *(const sx8*)(fe + 1536);

        fx4 accA[4], accB[4];
        #pragma unroll
        for (int ht = 0; ht < 4; ++ht) {
            accA[ht] = (fx4){hqr[ht][0], hqr[ht][1], hqr[ht][2], hqr[ht][3]};
            accB[ht] = accA[ht];
        }
        #pragma unroll
        for (int ht = 0; ht < 4; ++ht) {
            accA[ht] = __builtin_amdgcn_mfma_f32_16x16x32_bf16(afrag[ht][0], fa0, accA[ht], 0, 0, 0);
            accB[ht] = __builtin_amdgcn_mfma_f32_16x16x32_bf16(afrag[ht][0], fb0, accB[ht], 0, 0, 0);
        }
        #pragma unroll
        for (int ht = 0; ht < 4; ++ht) {
            accA[ht] = __builtin_amdgcn_mfma_f32_16x16x32_bf16(afrag[ht][1], fa1, accA[ht], 0, 0, 0);
            accB[ht] = __builtin_amdgcn_mfma_f32_16x16x32_bf16(afrag[ht][1], fb1, accB[ht], 0, 0, 0);
        }
        #pragma unroll
        for (int ht = 0; ht < 4; ++ht) {
            accA[ht] = __builtin_amdgcn_mfma_f32_16x16x32_bf16(oh[ht], (ht < 2) ? fa2 : fa3, accA[ht], 0, 0, 0);
            accB[ht] = __builtin_amdgcn_mfma_f32_16x16x32_bf16(oh[ht], (ht < 2) ? fb2 : fb3, accB[ht], 0, 0, 0);
        }

        // PReLU + W2 dot (h split across quads; reduce over quads)
        float s0 = 0.f, s1 = 0.f;
        #pragma unroll
        for (int ht = 0; ht < 4; ++ht)
            #pragma unroll
            for (int r = 0; r < 4; ++r) {
                float za = accA[ht][r];
                float zb = accB[ht][r];
                s0 = fmaf(w2r[ht][r], fmaf(pa, fminf(za, 0.f), fmaxf(za, 0.f)), s0);
                s1 = fmaf(w2r[ht][r], fmaf(pa, fminf(zb, 0.f), fmaxf(zb, 0.f)), s1);
            }
        s0 += __shfl_xor(s0, 16, 64);
        s0 += __shfl_xor(s0, 32, 64);
        s1 += __shfl_xor(s1, 16, 64);
        s1 += __shfl_xor(s1, 32, 64);
        int k0 = c * 32 + n;
        s0 = (k0 <= q)      ? s0 + b2v : 0.f;
        s1 = (k0 + 16 <= q) ? s1 + b2v : 0.f;

        // scores -> A-frag (k-layout) via bpermute of packed bf16 pair
        unsigned packed = (unsigned)f2bf(s0) | ((unsigned)f2bf(s1) << 16);
        int g[8];
        #pragma unroll
        for (int j = 0; j < 8; ++j)
            g[j] = __builtin_amdgcn_ds_bpermute(idxs[j], (int)packed);
        ix4 sw;
        sw[0] = (int)__builtin_amdgcn_perm((unsigned)g[1], (unsigned)g[0], sel);
        sw[1] = (int)__builtin_amdgcn_perm((unsigned)g[3], (unsigned)g[2], sel);
        sw[2] = (int)__builtin_amdgcn_perm((unsigned)g[5], (unsigned)g[4], sel);
        sw[3] = (int)__builtin_amdgcn_perm((unsigned)g[7], (unsigned)g[6], sel);
        sx8 sfrag = __builtin_bit_cast(sx8, sw);

        eacc[0] = __builtin_amdgcn_mfma_f32_16x16x32_bf16(sfrag, e0, eacc[0], 0, 0, 0);
        eacc[1] = __builtin_amdgcn_mfma_f32_16x16x32_bf16(sfrag, e1, eacc[1], 0, 0, 0);
        eacc[2] = __builtin_amdgcn_mfma_f32_16x16x32_bf16(sfrag, e2, eacc[2], 0, 0, 0);
        eacc[3] = __builtin_amdgcn_mfma_f32_16x16x32_bf16(sfrag, e3, eacc[3], 0, 0, 0);
    }

    // all m-rows of eacc are identical; lane's d = quad*16+n = lane
    float ov = eacc[0][0];
    if (quad == 1) ov = eacc[1][0];
    if (quad == 2) ov = eacc[2][0];
    if (quad == 3) ov = eacc[3][0];
    red[tid] = ov;
    __syncthreads();
    if (tid < 64)
        out[bq * 64 + tid] = red[tid] + red[64 + tid] + red[128 + tid] + red[192 + tid];
}

extern "C" void kernel_launch(void* const* d_in, const int* in_sizes, int n_in,
                              void* d_out, int out_size, void* d_ws, size_t ws_size,
                              hipStream_t stream) {
    const float* x   = (const float*)d_in[1];
    const float* vmk = (const float*)d_in[2];
    const float* W1  = (const float*)d_in[3];
    const float* b1  = (const float*)d_in[4];
    const float* pa  = (const float*)d_in[5];
    const float* W2  = (const float*)d_in[6];
    const float* b2  = (const float*)d_in[7];
    float* ws  = (float*)d_ws;
    float* out = (float*)d_out;

    hipLaunchKernelGGL(prep, dim3(NB * NN / 4), dim3(256), 0, stream,
                       x, vmk, W1, b1, ws);
    hipLaunchKernelGGL(k2_main, dim3(NB * NN), dim3(256), 0, stream,
                       x, pa, W2, b2, ws, out);
}

// Round 6
// 120.296 us; speedup vs baseline: 1.0131x; 1.0131x over previous
//
#include <hip/hip_runtime.h>

// DIN encoder. B=8, N=512, D=64, H=64. Two launches:
//   prep   — weight transforms, hq, hk-scatter, X B-frags, enc-X B-frags
//   k2_main— one wave per (b,q); 32 keys/chunk via MFMA; scores -> LDS;
//            decoupled second loop does the encoded GEMM from LDS scores.
// R3 lesson: (256,4) caps VGPR=64 -> 200MB scratch spill. Keep (256,2).
// R5 lesson: wave-splitting didn't help — iteration serial chain
//   (load->MFMA->VALU->shfl->bpermute->eacc-MFMA) was the binder (~2500
//   cyc/iter). R6 breaks the chain: no bpermute/eacc in the hot loop.
#define NB 8
#define NN 512

// ws layout (float offsets)
#define WS_WMF 0        // Wm A-frag-major fp32 [8 slot][64 lane][8]          4096
#define WS_HQ  4096     // hq fp32 [B*N][64]                                262144
#define WS_BF  266240   // B-frags bf16 [B][32 t][4 c][64 lane][8]   (262144 fl)
#define WS_XE  528384   // enc-X bf16 [B][16 c32][4 nt][64 lane][8]  (131072 fl)
// total 659456 floats = 2.64 MB

typedef float fx4 __attribute__((ext_vector_type(4)));
typedef short sx8 __attribute__((ext_vector_type(8)));
typedef int   ix4 __attribute__((ext_vector_type(4)));

static __device__ inline unsigned short f2bf(float f) {
    unsigned u = __float_as_uint(f);
    return (unsigned short)((u + 0x7FFFu + ((u >> 16) & 1u)) >> 16);  // RNE
}

// ---------------- fused prep ----------------
__global__ __launch_bounds__(256) void prep(const float* __restrict__ x,
                                            const float* __restrict__ vm,
                                            const float* __restrict__ W1,
                                            const float* __restrict__ b1,
                                            float* __restrict__ ws) {
    __shared__ float lwq[64 * 65];   // (Wq+Wd)^T  [d][h], pad 65
    __shared__ float lwk[64 * 65];   // (Wk-Wd)^T
    __shared__ float xs[256];
    const int t = threadIdx.x;
    const int blk = blockIdx.x;

    // stage weight combos, coalesced over d
    {
        int d = t & 63, hb = t >> 6;
        #pragma unroll 4
        for (int i = 0; i < 16; ++i) {
            int h = i * 4 + hb;
            float a = W1[h * 256 + d];
            float bb = W1[h * 256 + 64 + d];
            float c = W1[h * 256 + 128 + d];
            lwq[d * 65 + h] = a + c;
            lwk[d * 65 + h] = bb - c;
        }
    }
    const int r0 = blk * 4;
    xs[t] = x[r0 * 64 + t];
    __syncthreads();

    // hq + hk for this block's 4 rows
    {
        int r = t >> 6, h = t & 63;
        const float* xr = xs + r * 64;
        float aq = b1[h], ak = 0.f;
        #pragma unroll
        for (int dd = 0; dd < 64; ++dd) {
            float xv = xr[dd];
            aq = fmaf(xv, lwq[dd * 65 + h], aq);
            ak = fmaf(xv, lwk[dd * 65 + h], ak);
        }
        int row = r0 + r;
        (ws + WS_HQ)[row * 64 + h] = aq;
        // scatter hk into B-frag chunk c=2+(h>>5)
        unsigned short* bfp = (unsigned short*)(ws + WS_BF);
        int bb = row >> 9, k = row & 511;
        int tt = k >> 4, nn = k & 15;
        int c = 2 + (h >> 5);
        int qd = (h >> 3) & 3, j = h & 7;
        int ln = qd * 16 + nn;
        bfp[((((bb * 32 + tt) * 4 + c) * 64 + ln) << 3) + j] = f2bf(ak);
    }

    if (blk < 256) {
        int b = blk >> 5, t5 = blk & 31;
        // X -> BF chunks 0/1
        if (t < 128) {
            unsigned short* bfp = (unsigned short*)(ws + WS_BF);
            int c = t >> 6, L = t & 63;
            int nn = L & 15, qd = L >> 4;
            const float* src = x + ((b * 512 + t5 * 16 + nn) * 64 + c * 32 + qd * 8);
            fx4 v0 = *(const fx4*)src;
            fx4 v1 = *(const fx4*)(src + 4);
            uint4 o;
            o.x = (unsigned)f2bf(v0[0]) | ((unsigned)f2bf(v0[1]) << 16);
            o.y = (unsigned)f2bf(v0[2]) | ((unsigned)f2bf(v0[3]) << 16);
            o.z = (unsigned)f2bf(v1[0]) | ((unsigned)f2bf(v1[1]) << 16);
            o.w = (unsigned)f2bf(v1[2]) | ((unsigned)f2bf(v1[3]) << 16);
            *(uint4*)(bfp + ((((b * 32 + t5) * 4 + c) * 64 + L) << 3)) = o;
        }
        // masked X -> enc B-frags (XE)
        {
            unsigned short* xep = (unsigned short*)(ws + WS_XE);
            int c32 = t5 >> 1, half = t5 & 1;
            int nt = t >> 6, r = t & 63;
            int L = half * 32 + (r & 31);
            int j0 = (r >> 5) * 4;
            int quad = L >> 4, nn = L & 15;
            unsigned short u[4];
            #pragma unroll
            for (int i = 0; i < 4; ++i) {
                int key = c32 * 32 + quad * 8 + j0 + i;
                float v = x[(b * 512 + key) * 64 + nt * 16 + nn] * vm[b * 512 + key];
                u[i] = f2bf(v);
            }
            uint2 o;
            o.x = (unsigned)u[0] | ((unsigned)u[1] << 16);
            o.y = (unsigned)u[2] | ((unsigned)u[3] << 16);
            *(uint2*)(xep + (((((b * 16 + c32) * 4 + nt) * 64 + L) << 3) + j0)) = o;
        }
    } else if (blk < 258) {
        // Wm A-fragment-major
        float* wmf = ws + WS_WMF;
        int e = (blk - 256) * 256 + t;       // 0..511
        int slot = e >> 6, lane = e & 63;
        int ht = slot >> 1, hf = slot & 1;
        int m = lane & 15, qd = lane >> 4;
        int h = ht * 16 + m;
        int dbase = hf * 32 + qd * 8;
        #pragma unroll
        for (int j = 0; j < 8; ++j)
            wmf[e * 8 + j] = W1[h * 256 + 192 + dbase + j];
    }
}

// ---------------- main: one wave per (b,q) ----------------
__global__ __launch_bounds__(256, 2) void k2_main(const float* __restrict__ x,
                                                  const float* __restrict__ prelu_a,
                                                  const float* __restrict__ W2,
                                                  const float* __restrict__ b2,
                                                  const float* __restrict__ ws,
                                                  float* __restrict__ out) {
    const int tid  = threadIdx.x;
    const int lane = tid & 63;
    const int w    = tid >> 6;
    const int wid  = blockIdx.x * 4 + w;
    const int b    = wid >> 9;
    const int rr   = wid & 511;
    const int q    = (rr & 1) ? (511 - (rr >> 1)) : (rr >> 1);  // balance
    const int n    = lane & 15, quad = lane >> 4;
    const int bq   = b * 512 + q;

    const float* wmf = ws + WS_WMF;
    const float* hq  = ws + WS_HQ;
    const unsigned short* bfp = (const unsigned short*)(ws + WS_BF);
    const unsigned short* xep = (const unsigned short*)(ws + WS_XE);

    const float pa  = prelu_a[0];
    const float b2v = b2[0];

    // per-wave score strip: [wave][chunk c][n] packed bf16 (s(c*32+n), s(c*32+16+n))
    __shared__ unsigned sjoint[4 * 256];
    unsigned* myS = sjoint + w * 256;

    // hq (acc init) and W2 registers: h = ht*16 + quad*4 + r
    float hqr[4][4], w2r[4][4];
    #pragma unroll
    for (int ht = 0; ht < 4; ++ht) {
        fx4 vh = *(const fx4*)(hq + bq * 64 + ht * 16 + quad * 4);
        fx4 vw = *(const fx4*)(W2 + ht * 16 + quad * 4);
        #pragma unroll
        for (int r = 0; r < 4; ++r) { hqr[ht][r] = vh[r]; w2r[ht][r] = vw[r]; }
    }

    // xq for A-frags: lane needs d = half*32 + quad*8 + j
    float xq[2][8];
    {
        const float* xp = x + bq * 64 + quad * 8;
        fx4 t0 = *(const fx4*)xp;
        fx4 t1 = *(const fx4*)(xp + 4);
        fx4 t2 = *(const fx4*)(xp + 32);
        fx4 t3 = *(const fx4*)(xp + 36);
        #pragma unroll
        for (int j = 0; j < 4; ++j) {
            xq[0][j] = t0[j]; xq[0][4 + j] = t1[j];
            xq[1][j] = t2[j]; xq[1][4 + j] = t3[j];
        }
    }

    // A-frags: Wm ⊙ xq (bf16)
    sx8 afrag[4][2];
    #pragma unroll
    for (int ht = 0; ht < 4; ++ht)
        #pragma unroll
        for (int hf = 0; hf < 2; ++hf) {
            const float* wp = wmf + (((ht * 2 + hf) * 64 + lane) << 3);
            fx4 w0 = *(const fx4*)wp;
            fx4 w1 = *(const fx4*)(wp + 4);
            sx8 a;
            #pragma unroll
            for (int j = 0; j < 4; ++j) {
                a[j]     = (short)f2bf(w0[j] * xq[hf][j]);
                a[4 + j] = (short)f2bf(w1[j] * xq[hf][4 + j]);
            }
            afrag[ht][hf] = a;
        }

    // one-hot A-frags for the hk fold
    sx8 oh[4];
    #pragma unroll
    for (int ht = 0; ht < 4; ++ht) {
        sx8 a;
        #pragma unroll
        for (int j = 0; j < 8; ++j) {
            int hp = (ht >> 1) * 32 + quad * 8 + j;
            a[j] = (hp == ht * 16 + n) ? (short)0x3F80 : (short)0;
        }
        oh[ht] = a;
    }

    const int cmax = q >> 5;

    // ---- score loop: no cross-lane except 4 shfl; ends in one LDS write ----
    for (int c = 0; c <= cmax; ++c) {
        const unsigned short* fb = bfp + ((((b * 32 + 2 * c) * 4) * 64 + lane) << 3);
        sx8 fa0 = *(const sx8*)(fb);
        sx8 fa1 = *(const sx8*)(fb + 512);
        sx8 fa2 = *(const sx8*)(fb + 1024);
        sx8 fa3 = *(const sx8*)(fb + 1536);
        sx8 fb0 = *(const sx8*)(fb + 2048);
        sx8 fb1 = *(const sx8*)(fb + 2560);
        sx8 fb2 = *(const sx8*)(fb + 3072);
        sx8 fb3 = *(const sx8*)(fb + 3584);

        fx4 accA[4], accB[4];
        #pragma unroll
        for (int ht = 0; ht < 4; ++ht) {
            accA[ht] = (fx4){hqr[ht][0], hqr[ht][1], hqr[ht][2], hqr[ht][3]};
            accB[ht] = accA[ht];
        }
        #pragma unroll
        for (int ht = 0; ht < 4; ++ht) {
            accA[ht] = __builtin_amdgcn_mfma_f32_16x16x32_bf16(afrag[ht][0], fa0, accA[ht], 0, 0, 0);
            accB[ht] = __builtin_amdgcn_mfma_f32_16x16x32_bf16(afrag[ht][0], fb0, accB[ht], 0, 0, 0);
        }
        #pragma unroll
        for (int ht = 0; ht < 4; ++ht) {
            accA[ht] = __builtin_amdgcn_mfma_f32_16x16x32_bf16(afrag[ht][1], fa1, accA[ht], 0, 0, 0);
            accB[ht] = __builtin_amdgcn_mfma_f32_16x16x32_bf16(afrag[ht][1], fb1, accB[ht], 0, 0, 0);
        }
        #pragma unroll
        for (int ht = 0; ht < 4; ++ht) {
            accA[ht] = __builtin_amdgcn_mfma_f32_16x16x32_bf16(oh[ht], (ht < 2) ? fa2 : fa3, accA[ht], 0, 0, 0);
            accB[ht] = __builtin_amdgcn_mfma_f32_16x16x32_bf16(oh[ht], (ht < 2) ? fb2 : fb3, accB[ht], 0, 0, 0);
        }

        // PReLU(z) = max(z, pa*z)  (pa>0); then W2 dot, split accumulators
        float s0a = 0.f, s0b = 0.f, s1a = 0.f, s1b = 0.f;
        #pragma unroll
        for (int ht = 0; ht < 2; ++ht)
            #pragma unroll
            for (int r = 0; r < 4; ++r) {
                float za = accA[ht][r], zb = accB[ht][r];
                s0a = fmaf(w2r[ht][r], fmaxf(za, za * pa), s0a);
                s1a = fmaf(w2r[ht][r], fmaxf(zb, zb * pa), s1a);
            }
        #pragma unroll
        for (int ht = 2; ht < 4; ++ht)
            #pragma unroll
            for (int r = 0; r < 4; ++r) {
                float za = accA[ht][r], zb = accB[ht][r];
                s0b = fmaf(w2r[ht][r], fmaxf(za, za * pa), s0b);
                s1b = fmaf(w2r[ht][r], fmaxf(zb, zb * pa), s1b);
            }
        float s0 = s0a + s0b, s1 = s1a + s1b;
        s0 += __shfl_xor(s0, 16, 64);
        s0 += __shfl_xor(s0, 32, 64);
        s1 += __shfl_xor(s1, 16, 64);
        s1 += __shfl_xor(s1, 32, 64);
        int k0 = c * 32 + n;
        s0 = (k0 <= q)      ? s0 + b2v : 0.f;
        s1 = (k0 + 16 <= q) ? s1 + b2v : 0.f;

        unsigned packed = (unsigned)f2bf(s0) | ((unsigned)f2bf(s1) << 16);
        if (quad == 0) myS[c * 16 + n] = packed;
    }

    // ---- decoupled encoded GEMM: scores (LDS) x XE, acc-chained MFMAs ----
    const unsigned sel = (quad < 2) ? 0x05040100u : 0x07060302u;
    fx4 eacc[4];
    #pragma unroll
    for (int nt = 0; nt < 4; ++nt) eacc[nt] = (fx4){0.f, 0.f, 0.f, 0.f};

    for (int c = 0; c <= cmax; ++c) {
        const unsigned* sp = myS + c * 16 + (quad & 1) * 8;
        uint4 wv0 = *(const uint4*)sp;        // words for keys (quad&1)*8 .. +3
        uint4 wv1 = *(const uint4*)(sp + 4);  // .. +7
        ix4 sw;
        sw[0] = (int)__builtin_amdgcn_perm(wv0.y, wv0.x, sel);
        sw[1] = (int)__builtin_amdgcn_perm(wv0.w, wv0.z, sel);
        sw[2] = (int)__builtin_amdgcn_perm(wv1.y, wv1.x, sel);
        sw[3] = (int)__builtin_amdgcn_perm(wv1.w, wv1.z, sel);
        sx8 sfrag = __builtin_bit_cast(sx8, sw);

        const unsigned short* fe = xep + ((((b * 16 + c) * 4) * 64 + lane) << 3);
        sx8 e0 = *(const sx8*)(fe);
        sx8 e1 = *(const sx8*)(fe + 512);
        sx8 e2 = *(const sx8*)(fe + 1024);
        sx8 e3 = *(const sx8*)(fe + 1536);

        eacc[0] = __builtin_amdgcn_mfma_f32_16x16x32_bf16(sfrag, e0, eacc[0], 0, 0, 0);
        eacc[1] = __builtin_amdgcn_mfma_f32_16x16x32_bf16(sfrag, e1, eacc[1], 0, 0, 0);
        eacc[2] = __builtin_amdgcn_mfma_f32_16x16x32_bf16(sfrag, e2, eacc[2], 0, 0, 0);
        eacc[3] = __builtin_amdgcn_mfma_f32_16x16x32_bf16(sfrag, e3, eacc[3], 0, 0, 0);
    }

    // all m-rows identical; lane's d = quad*16 + n
    float ov = eacc[0][0];
    if (quad == 1) ov = eacc[1][0];
    if (quad == 2) ov = eacc[2][0];
    if (quad == 3) ov = eacc[3][0];
    out[bq * 64 + quad * 16 + n] = ov;
}

extern "C" void kernel_launch(void* const* d_in, const int* in_sizes, int n_in,
                              void* d_out, int out_size, void* d_ws, size_t ws_size,
                              hipStream_t stream) {
    const float* x   = (const float*)d_in[1];
    const float* vmk = (const float*)d_in[2];
    const float* W1  = (const float*)d_in[3];
    const float* b1  = (const float*)d_in[4];
    const float* pa  = (const float*)d_in[5];
    const float* W2  = (const float*)d_in[6];
    const float* b2  = (const float*)d_in[7];
    float* ws  = (float*)d_ws;
    float* out = (float*)d_out;

    hipLaunchKernelGGL(prep, dim3(NB * NN / 4), dim3(256), 0, stream,
                       x, vmk, W1, b1, ws);
    hipLaunchKernelGGL(k2_main, dim3(NB * NN / 4), dim3(256), 0, stream,
                       x, pa, W2, b2, ws, out);
}

// Round 7
// 108.817 us; speedup vs baseline: 1.1200x; 1.1055x over previous
//
#include <hip/hip_runtime.h>

// DIN encoder. B=8, N=512, D=64, H=64. Two launches:
//   prep   — weight transforms, hq, hk-scatter, X B-frags, enc-X B-frags
//   k2_main— one BLOCK per 8 queries (4 low + 4 high paired, same b);
//            key-chunk fragments staged once into LDS (double-buffered),
//            8 waves consume them. Score+enc per chunk as R6/R4 (proven).
// R3 lesson: VGPR cap 64 -> 200MB scratch spill. Bounds (512,2) only.
// R6 lesson: ~50µs across 3 inner-loop shapes = L2 traffic/latency bound
//   (each wave streamed ~126KB from L2, zero reuse). R7 stages keys in LDS
//   shared by 8 queries -> 8x L2 traffic cut, LDS-source fragments.
#define NB 8
#define NN 512

// ws layout (float offsets)
#define WS_WMF 0        // Wm A-frag-major fp32 [8 slot][64 lane][8]          4096
#define WS_HQ  4096     // hq fp32 [B*N][64]                                262144
#define WS_BF  266240   // B-frags bf16 [B][32 t][4 c][64 lane][8]   (262144 fl)
#define WS_XE  528384   // enc-X bf16 [B][16 c32][4 nt][64 lane][8]  (131072 fl)
// total 659456 floats = 2.64 MB

typedef float fx4 __attribute__((ext_vector_type(4)));
typedef short sx8 __attribute__((ext_vector_type(8)));
typedef int   ix4 __attribute__((ext_vector_type(4)));

static __device__ inline unsigned short f2bf(float f) {
    unsigned u = __float_as_uint(f);
    return (unsigned short)((u + 0x7FFFu + ((u >> 16) & 1u)) >> 16);  // RNE
}

// ---------------- fused prep ----------------
__global__ __launch_bounds__(256) void prep(const float* __restrict__ x,
                                            const float* __restrict__ vm,
                                            const float* __restrict__ W1,
                                            const float* __restrict__ b1,
                                            float* __restrict__ ws) {
    __shared__ float lwq[64 * 65];   // (Wq+Wd)^T  [d][h], pad 65
    __shared__ float lwk[64 * 65];   // (Wk-Wd)^T
    __shared__ float xs[256];
    const int t = threadIdx.x;
    const int blk = blockIdx.x;

    // stage weight combos, coalesced over d
    {
        int d = t & 63, hb = t >> 6;
        #pragma unroll 4
        for (int i = 0; i < 16; ++i) {
            int h = i * 4 + hb;
            float a = W1[h * 256 + d];
            float bb = W1[h * 256 + 64 + d];
            float c = W1[h * 256 + 128 + d];
            lwq[d * 65 + h] = a + c;
            lwk[d * 65 + h] = bb - c;
        }
    }
    const int r0 = blk * 4;
    xs[t] = x[r0 * 64 + t];
    __syncthreads();

    // hq + hk for this block's 4 rows
    {
        int r = t >> 6, h = t & 63;
        const float* xr = xs + r * 64;
        float aq = b1[h], ak = 0.f;
        #pragma unroll
        for (int dd = 0; dd < 64; ++dd) {
            float xv = xr[dd];
            aq = fmaf(xv, lwq[dd * 65 + h], aq);
            ak = fmaf(xv, lwk[dd * 65 + h], ak);
        }
        int row = r0 + r;
        (ws + WS_HQ)[row * 64 + h] = aq;
        // scatter hk into B-frag chunk c=2+(h>>5)
        unsigned short* bfp = (unsigned short*)(ws + WS_BF);
        int bb = row >> 9, k = row & 511;
        int tt = k >> 4, nn = k & 15;
        int c = 2 + (h >> 5);
        int qd = (h >> 3) & 3, j = h & 7;
        int ln = qd * 16 + nn;
        bfp[((((bb * 32 + tt) * 4 + c) * 64 + ln) << 3) + j] = f2bf(ak);
    }

    if (blk < 256) {
        int b = blk >> 5, t5 = blk & 31;
        // X -> BF chunks 0/1
        if (t < 128) {
            unsigned short* bfp = (unsigned short*)(ws + WS_BF);
            int c = t >> 6, L = t & 63;
            int nn = L & 15, qd = L >> 4;
            const float* src = x + ((b * 512 + t5 * 16 + nn) * 64 + c * 32 + qd * 8);
            fx4 v0 = *(const fx4*)src;
            fx4 v1 = *(const fx4*)(src + 4);
            uint4 o;
            o.x = (unsigned)f2bf(v0[0]) | ((unsigned)f2bf(v0[1]) << 16);
            o.y = (unsigned)f2bf(v0[2]) | ((unsigned)f2bf(v0[3]) << 16);
            o.z = (unsigned)f2bf(v1[0]) | ((unsigned)f2bf(v1[1]) << 16);
            o.w = (unsigned)f2bf(v1[2]) | ((unsigned)f2bf(v1[3]) << 16);
            *(uint4*)(bfp + ((((b * 32 + t5) * 4 + c) * 64 + L) << 3)) = o;
        }
        // masked X -> enc B-frags (XE)
        {
            unsigned short* xep = (unsigned short*)(ws + WS_XE);
            int c32 = t5 >> 1, half = t5 & 1;
            int nt = t >> 6, r = t & 63;
            int L = half * 32 + (r & 31);
            int j0 = (r >> 5) * 4;
            int quad = L >> 4, nn = L & 15;
            unsigned short u[4];
            #pragma unroll
            for (int i = 0; i < 4; ++i) {
                int key = c32 * 32 + quad * 8 + j0 + i;
                float v = x[(b * 512 + key) * 64 + nt * 16 + nn] * vm[b * 512 + key];
                u[i] = f2bf(v);
            }
            uint2 o;
            o.x = (unsigned)u[0] | ((unsigned)u[1] << 16);
            o.y = (unsigned)u[2] | ((unsigned)u[3] << 16);
            *(uint2*)(xep + (((((b * 16 + c32) * 4 + nt) * 64 + L) << 3) + j0)) = o;
        }
    } else if (blk < 258) {
        // Wm A-fragment-major
        float* wmf = ws + WS_WMF;
        int e = (blk - 256) * 256 + t;       // 0..511
        int slot = e >> 6, lane = e & 63;
        int ht = slot >> 1, hf = slot & 1;
        int m = lane & 15, qd = lane >> 4;
        int h = ht * 16 + m;
        int dbase = hf * 32 + qd * 8;
        #pragma unroll
        for (int j = 0; j < 8; ++j)
            wmf[e * 8 + j] = W1[h * 256 + 192 + dbase + j];
    }
}

// ------- main: 8 waves = 8 queries/block; LDS-staged key fragments -------
__global__ __launch_bounds__(512, 2) void k2_main(const float* __restrict__ x,
                                                  const float* __restrict__ prelu_a,
                                                  const float* __restrict__ W2,
                                                  const float* __restrict__ b2,
                                                  const float* __restrict__ ws,
                                                  float* __restrict__ out) {
    const int tid  = threadIdx.x;
    const int lane = tid & 63;
    const int w    = tid >> 6;            // 0..7
    const int blk  = blockIdx.x;
    const int b    = blk >> 6;
    const int j    = blk & 63;
    const int q    = (w < 4) ? (4 * j + w) : (508 - 4 * j + (w - 4));
    const int n    = lane & 15, quad = lane >> 4;
    const int bq   = b * 512 + q;
    const int cmaxw = q >> 5;
    const int cblk  = (511 - 4 * j) >> 5;   // block-uniform round count

    const float* wmf = ws + WS_WMF;
    const float* hq  = ws + WS_HQ;
    const unsigned short* bfp = (const unsigned short*)(ws + WS_BF);
    const unsigned short* xep = (const unsigned short*)(ws + WS_XE);

    const float pa  = prelu_a[0];
    const float b2v = b2[0];

    __shared__ uint4 bufS[2][512];   // score frags: 2 tiles x 4 c x 64 x 8 bf16
    __shared__ uint4 bufE[2][256];   // enc-X frags: 4 nt x 64 x 8 bf16

    // hq (acc init) and W2 registers: h = ht*16 + quad*4 + r
    float hqr[4][4], w2r[4][4];
    #pragma unroll
    for (int ht = 0; ht < 4; ++ht) {
        fx4 vh = *(const fx4*)(hq + bq * 64 + ht * 16 + quad * 4);
        fx4 vw = *(const fx4*)(W2 + ht * 16 + quad * 4);
        #pragma unroll
        for (int r = 0; r < 4; ++r) { hqr[ht][r] = vh[r]; w2r[ht][r] = vw[r]; }
    }

    // xq for A-frags: lane needs d = half*32 + quad*8 + jj
    float xq[2][8];
    {
        const float* xp = x + bq * 64 + quad * 8;
        fx4 t0 = *(const fx4*)xp;
        fx4 t1 = *(const fx4*)(xp + 4);
        fx4 t2 = *(const fx4*)(xp + 32);
        fx4 t3 = *(const fx4*)(xp + 36);
        #pragma unroll
        for (int jj = 0; jj < 4; ++jj) {
            xq[0][jj] = t0[jj]; xq[0][4 + jj] = t1[jj];
            xq[1][jj] = t2[jj]; xq[1][4 + jj] = t3[jj];
        }
    }

    // A-frags: Wm ⊙ xq (bf16)
    sx8 afrag[4][2];
    #pragma unroll
    for (int ht = 0; ht < 4; ++ht)
        #pragma unroll
        for (int hf = 0; hf < 2; ++hf) {
            const float* wp = wmf + (((ht * 2 + hf) * 64 + lane) << 3);
            fx4 w0 = *(const fx4*)wp;
            fx4 w1 = *(const fx4*)(wp + 4);
            sx8 a;
            #pragma unroll
            for (int jj = 0; jj < 4; ++jj) {
                a[jj]     = (short)f2bf(w0[jj] * xq[hf][jj]);
                a[4 + jj] = (short)f2bf(w1[jj] * xq[hf][4 + jj]);
            }
            afrag[ht][hf] = a;
        }

    // one-hot A-frags for the hk fold
    sx8 oh[4];
    #pragma unroll
    for (int ht = 0; ht < 4; ++ht) {
        sx8 a;
        #pragma unroll
        for (int jj = 0; jj < 8; ++jj) {
            int hp = (ht >> 1) * 32 + quad * 8 + jj;
            a[jj] = (hp == ht * 16 + n) ? (short)0x3F80 : (short)0;
        }
        oh[ht] = a;
    }

    // score -> enc A-frag gather constants
    int idxs[8];
    #pragma unroll
    for (int jj = 0; jj < 8; ++jj) idxs[jj] = ((quad * 8 + jj) & 15) << 2;
    const unsigned sel = (quad < 2) ? 0x05040100u : 0x07060302u;

    fx4 eacc[4];
    #pragma unroll
    for (int nt = 0; nt < 4; ++nt) eacc[nt] = (fx4){0.f, 0.f, 0.f, 0.f};

    // stage chunk 0
    {
        const uint4* s = (const uint4*)(bfp + (unsigned)(b * 32) * 2048);
        bufS[0][tid] = s[tid];
        if (tid < 256) {
            const uint4* s2 = (const uint4*)(xep + (unsigned)(b * 16) * 2048);
            bufE[0][tid] = s2[tid];
        }
    }
    __syncthreads();

    for (int c = 0; c <= cblk; ++c) {
        // issue next chunk's global loads into registers (latency hidden by compute)
        uint4 st, st2;
        if (c < cblk) {
            int cc = c + 1;
            st = ((const uint4*)(bfp + (unsigned)(b * 32 + 2 * cc) * 2048))[tid];
            if (tid < 256)
                st2 = ((const uint4*)(xep + (unsigned)(b * 16 + cc) * 2048))[tid];
        }

        if (c <= cmaxw) {
            const unsigned short* ls = (const unsigned short*)&bufS[c & 1][0] + lane * 8;
            sx8 fa0 = *(const sx8*)(ls);
            sx8 fa1 = *(const sx8*)(ls + 512);
            sx8 fa2 = *(const sx8*)(ls + 1024);
            sx8 fa3 = *(const sx8*)(ls + 1536);
            sx8 fb0 = *(const sx8*)(ls + 2048);
            sx8 fb1 = *(const sx8*)(ls + 2560);
            sx8 fb2 = *(const sx8*)(ls + 3072);
            sx8 fb3 = *(const sx8*)(ls + 3584);

            fx4 accA[4], accB[4];
            #pragma unroll
            for (int ht = 0; ht < 4; ++ht) {
                accA[ht] = (fx4){hqr[ht][0], hqr[ht][1], hqr[ht][2], hqr[ht][3]};
                accB[ht] = accA[ht];
            }
            #pragma unroll
            for (int ht = 0; ht < 4; ++ht) {
                accA[ht] = __builtin_amdgcn_mfma_f32_16x16x32_bf16(afrag[ht][0], fa0, accA[ht], 0, 0, 0);
                accB[ht] = __builtin_amdgcn_mfma_f32_16x16x32_bf16(afrag[ht][0], fb0, accB[ht], 0, 0, 0);
            }
            #pragma unroll
            for (int ht = 0; ht < 4; ++ht) {
                accA[ht] = __builtin_amdgcn_mfma_f32_16x16x32_bf16(afrag[ht][1], fa1, accA[ht], 0, 0, 0);
                accB[ht] = __builtin_amdgcn_mfma_f32_16x16x32_bf16(afrag[ht][1], fb1, accB[ht], 0, 0, 0);
            }
            #pragma unroll
            for (int ht = 0; ht < 4; ++ht) {
                accA[ht] = __builtin_amdgcn_mfma_f32_16x16x32_bf16(oh[ht], (ht < 2) ? fa2 : fa3, accA[ht], 0, 0, 0);
                accB[ht] = __builtin_amdgcn_mfma_f32_16x16x32_bf16(oh[ht], (ht < 2) ? fb2 : fb3, accB[ht], 0, 0, 0);
            }

            // PReLU(z)=max(z, pa*z); W2 dot (h split over quads), reduce
            float s0a = 0.f, s0b = 0.f, s1a = 0.f, s1b = 0.f;
            #pragma unroll
            for (int ht = 0; ht < 2; ++ht)
                #pragma unroll
                for (int r = 0; r < 4; ++r) {
                    float za = accA[ht][r], zb = accB[ht][r];
                    s0a = fmaf(w2r[ht][r], fmaxf(za, za * pa), s0a);
                    s1a = fmaf(w2r[ht][r], fmaxf(zb, zb * pa), s1a);
                }
            #pragma unroll
            for (int ht = 2; ht < 4; ++ht)
                #pragma unroll
                for (int r = 0; r < 4; ++r) {
                    float za = accA[ht][r], zb = accB[ht][r];
                    s0b = fmaf(w2r[ht][r], fmaxf(za, za * pa), s0b);
                    s1b = fmaf(w2r[ht][r], fmaxf(zb, zb * pa), s1b);
                }
            float s0 = s0a + s0b, s1 = s1a + s1b;
            s0 += __shfl_xor(s0, 16, 64);
            s0 += __shfl_xor(s0, 32, 64);
            s1 += __shfl_xor(s1, 16, 64);
            s1 += __shfl_xor(s1, 32, 64);
            int k0 = c * 32 + n;
            s0 = (k0 <= q)      ? s0 + b2v : 0.f;
            s1 = (k0 + 16 <= q) ? s1 + b2v : 0.f;

            // scores -> A-frag (k-layout) via bpermute of packed bf16 pair
            unsigned packed = (unsigned)f2bf(s0) | ((unsigned)f2bf(s1) << 16);
            int g[8];
            #pragma unroll
            for (int jj = 0; jj < 8; ++jj)
                g[jj] = __builtin_amdgcn_ds_bpermute(idxs[jj], (int)packed);
            ix4 sw_;
            sw_[0] = (int)__builtin_amdgcn_perm((unsigned)g[1], (unsigned)g[0], sel);
            sw_[1] = (int)__builtin_amdgcn_perm((unsigned)g[3], (unsigned)g[2], sel);
            sw_[2] = (int)__builtin_amdgcn_perm((unsigned)g[5], (unsigned)g[4], sel);
            sw_[3] = (int)__builtin_amdgcn_perm((unsigned)g[7], (unsigned)g[6], sel);
            sx8 sfrag = __builtin_bit_cast(sx8, sw_);

            const unsigned short* le = (const unsigned short*)&bufE[c & 1][0] + lane * 8;
            sx8 e0 = *(const sx8*)(le);
            sx8 e1 = *(const sx8*)(le + 512);
            sx8 e2 = *(const sx8*)(le + 1024);
            sx8 e3 = *(const sx8*)(le + 1536);

            eacc[0] = __builtin_amdgcn_mfma_f32_16x16x32_bf16(sfrag, e0, eacc[0], 0, 0, 0);
            eacc[1] = __builtin_amdgcn_mfma_f32_16x16x32_bf16(sfrag, e1, eacc[1], 0, 0, 0);
            eacc[2] = __builtin_amdgcn_mfma_f32_16x16x32_bf16(sfrag, e2, eacc[2], 0, 0, 0);
            eacc[3] = __builtin_amdgcn_mfma_f32_16x16x32_bf16(sfrag, e3, eacc[3], 0, 0, 0);
        }

        // commit next chunk to LDS (after compute; before barrier)
        if (c < cblk) {
            int cc = c + 1;
            bufS[cc & 1][tid] = st;
            if (tid < 256) bufE[cc & 1][tid] = st2;
        }
        __syncthreads();
    }

    // all m-rows identical; lane's d = quad*16 + n = lane
    float ov = eacc[0][0];
    if (quad == 1) ov = eacc[1][0];
    if (quad == 2) ov = eacc[2][0];
    if (quad == 3) ov = eacc[3][0];
    out[bq * 64 + lane] = ov;
}

extern "C" void kernel_launch(void* const* d_in, const int* in_sizes, int n_in,
                              void* d_out, int out_size, void* d_ws, size_t ws_size,
                              hipStream_t stream) {
    const float* x   = (const float*)d_in[1];
    const float* vmk = (const float*)d_in[2];
    const float* W1  = (const float*)d_in[3];
    const float* b1  = (const float*)d_in[4];
    const float* pa  = (const float*)d_in[5];
    const float* W2  = (const float*)d_in[6];
    const float* b2  = (const float*)d_in[7];
    float* ws  = (float*)d_ws;
    float* out = (float*)d_out;

    hipLaunchKernelGGL(prep, dim3(NB * NN / 4), dim3(256), 0, stream,
                       x, vmk, W1, b1, ws);
    hipLaunchKernelGGL(k2_main, dim3(NB * 64), dim3(512), 0, stream,
                       x, pa, W2, b2, ws, out);
}

// Round 8
// 103.106 us; speedup vs baseline: 1.1820x; 1.0554x over previous
//
#include <hip/hip_runtime.h>

// DIN encoder. B=8, N=512, D=64, H=64. Two launches:
//   prep   — weight transforms, hq, hk-scatter, X B-frags, enc-X B-frags
//   k2_main— 512 UNIFORM blocks × 256 thr (4 waves). Block = (b, m, s):
//            phase A = 4 queries of band m (chunks 0..m), phase B = 4
//            queries of band 15-m (chunks 0..15-m) -> 17 rounds/block,
//            every wave active every round (R7 wasted 32% on idle waves).
//            Key-chunk frags staged once/block into LDS (double-buffered).
// R3 lesson: tight VGPR caps -> 200MB scratch spill. R7 measured VGPR=92,
//            so (256,2) is safe. R6 lesson: strip-via-LDS beats bpermute.
#define NB 8
#define NN 512

// ws layout (float offsets)
#define WS_WMF 0        // Wm A-frag-major fp32 [8 slot][64 lane][8]          4096
#define WS_HQ  4096     // hq fp32 [B*N][64]                                262144
#define WS_BF  266240   // B-frags bf16 [B][32 t][4 c][64 lane][8]   (262144 fl)
#define WS_XE  528384   // enc-X bf16 [B][16 c32][4 nt][64 lane][8]  (131072 fl)
// total 659456 floats = 2.64 MB

typedef float fx4 __attribute__((ext_vector_type(4)));
typedef short sx8 __attribute__((ext_vector_type(8)));
typedef int   ix4 __attribute__((ext_vector_type(4)));

static __device__ inline unsigned short f2bf(float f) {
    unsigned u = __float_as_uint(f);
    return (unsigned short)((u + 0x7FFFu + ((u >> 16) & 1u)) >> 16);  // RNE
}

// ---------------- fused prep ----------------
__global__ __launch_bounds__(256) void prep(const float* __restrict__ x,
                                            const float* __restrict__ vm,
                                            const float* __restrict__ W1,
                                            const float* __restrict__ b1,
                                            float* __restrict__ ws) {
    __shared__ float lwq[64 * 65];   // (Wq+Wd)^T  [d][h], pad 65
    __shared__ float lwk[64 * 65];   // (Wk-Wd)^T
    __shared__ float xs[256];
    const int t = threadIdx.x;
    const int blk = blockIdx.x;

    // stage weight combos, coalesced over d
    {
        int d = t & 63, hb = t >> 6;
        #pragma unroll 4
        for (int i = 0; i < 16; ++i) {
            int h = i * 4 + hb;
            float a = W1[h * 256 + d];
            float bb = W1[h * 256 + 64 + d];
            float c = W1[h * 256 + 128 + d];
            lwq[d * 65 + h] = a + c;
            lwk[d * 65 + h] = bb - c;
        }
    }
    const int r0 = blk * 4;
    xs[t] = x[r0 * 64 + t];
    __syncthreads();

    // hq + hk for this block's 4 rows
    {
        int r = t >> 6, h = t & 63;
        const float* xr = xs + r * 64;
        float aq = b1[h], ak = 0.f;
        #pragma unroll
        for (int dd = 0; dd < 64; ++dd) {
            float xv = xr[dd];
            aq = fmaf(xv, lwq[dd * 65 + h], aq);
            ak = fmaf(xv, lwk[dd * 65 + h], ak);
        }
        int row = r0 + r;
        (ws + WS_HQ)[row * 64 + h] = aq;
        // scatter hk into B-frag chunk c=2+(h>>5)
        unsigned short* bfp = (unsigned short*)(ws + WS_BF);
        int bb = row >> 9, k = row & 511;
        int tt = k >> 4, nn = k & 15;
        int c = 2 + (h >> 5);
        int qd = (h >> 3) & 3, j = h & 7;
        int ln = qd * 16 + nn;
        bfp[((((bb * 32 + tt) * 4 + c) * 64 + ln) << 3) + j] = f2bf(ak);
    }

    if (blk < 256) {
        int b = blk >> 5, t5 = blk & 31;
        // X -> BF chunks 0/1
        if (t < 128) {
            unsigned short* bfp = (unsigned short*)(ws + WS_BF);
            int c = t >> 6, L = t & 63;
            int nn = L & 15, qd = L >> 4;
            const float* src = x + ((b * 512 + t5 * 16 + nn) * 64 + c * 32 + qd * 8);
            fx4 v0 = *(const fx4*)src;
            fx4 v1 = *(const fx4*)(src + 4);
            uint4 o;
            o.x = (unsigned)f2bf(v0[0]) | ((unsigned)f2bf(v0[1]) << 16);
            o.y = (unsigned)f2bf(v0[2]) | ((unsigned)f2bf(v0[3]) << 16);
            o.z = (unsigned)f2bf(v1[0]) | ((unsigned)f2bf(v1[1]) << 16);
            o.w = (unsigned)f2bf(v1[2]) | ((unsigned)f2bf(v1[3]) << 16);
            *(uint4*)(bfp + ((((b * 32 + t5) * 4 + c) * 64 + L) << 3)) = o;
        }
        // masked X -> enc B-frags (XE)
        {
            unsigned short* xep = (unsigned short*)(ws + WS_XE);
            int c32 = t5 >> 1, half = t5 & 1;
            int nt = t >> 6, r = t & 63;
            int L = half * 32 + (r & 31);
            int j0 = (r >> 5) * 4;
            int quad = L >> 4, nn = L & 15;
            unsigned short u[4];
            #pragma unroll
            for (int i = 0; i < 4; ++i) {
                int key = c32 * 32 + quad * 8 + j0 + i;
                float v = x[(b * 512 + key) * 64 + nt * 16 + nn] * vm[b * 512 + key];
                u[i] = f2bf(v);
            }
            uint2 o;
            o.x = (unsigned)u[0] | ((unsigned)u[1] << 16);
            o.y = (unsigned)u[2] | ((unsigned)u[3] << 16);
            *(uint2*)(xep + (((((b * 16 + c32) * 4 + nt) * 64 + L) << 3) + j0)) = o;
        }
    } else if (blk < 258) {
        // Wm A-fragment-major
        float* wmf = ws + WS_WMF;
        int e = (blk - 256) * 256 + t;       // 0..511
        int slot = e >> 6, lane = e & 63;
        int ht = slot >> 1, hf = slot & 1;
        int m = lane & 15, qd = lane >> 4;
        int h = ht * 16 + m;
        int dbase = hf * 32 + qd * 8;
        #pragma unroll
        for (int j = 0; j < 8; ++j)
            wmf[e * 8 + j] = W1[h * 256 + 192 + dbase + j];
    }
}

// ------- main: uniform 17-round blocks; band m then band 15-m -------
__global__ __launch_bounds__(256, 2) void k2_main(const float* __restrict__ x,
                                                  const float* __restrict__ prelu_a,
                                                  const float* __restrict__ W2,
                                                  const float* __restrict__ b2,
                                                  const float* __restrict__ ws,
                                                  float* __restrict__ out) {
    const int tid  = threadIdx.x;
    const int lane = tid & 63;
    const int w    = tid >> 6;            // 0..3
    const int blk  = blockIdx.x;
    const int b    = blk >> 6;
    const int rest = blk & 63;
    const int m    = rest >> 3;           // 0..7: band pair (m, 15-m)
    const int s    = rest & 7;            // 0..7: 4-query slice within band
    const int n    = lane & 15, quad = lane >> 4;

    const float* wmf = ws + WS_WMF;
    const float* hq  = ws + WS_HQ;
    const unsigned short* bfp = (const unsigned short*)(ws + WS_BF);
    const unsigned short* xep = (const unsigned short*)(ws + WS_XE);

    const float pa  = prelu_a[0];
    const float b2v = b2[0];

    __shared__ uint4 bufS[2][512];     // score frags: 8 KB per buffer
    __shared__ uint4 bufE[2][256];     // enc-X frags: 4 KB per buffer
    __shared__ unsigned strip[4][16];  // per-wave packed score strip

    // phase-independent: W2, one-hot, perm sel
    float w2r[4][4];
    #pragma unroll
    for (int ht = 0; ht < 4; ++ht) {
        fx4 vw = *(const fx4*)(W2 + ht * 16 + quad * 4);
        #pragma unroll
        for (int r = 0; r < 4; ++r) w2r[ht][r] = vw[r];
    }
    sx8 oh[4];
    #pragma unroll
    for (int ht = 0; ht < 4; ++ht) {
        sx8 a;
        #pragma unroll
        for (int jj = 0; jj < 8; ++jj) {
            int hp = (ht >> 1) * 32 + quad * 8 + jj;
            a[jj] = (hp == ht * 16 + n) ? (short)0x3F80 : (short)0;
        }
        oh[ht] = a;
    }
    const unsigned sel = (quad < 2) ? 0x05040100u : 0x07060302u;

    // stage round 0 (phase A chunk 0)
    {
        const uint4* srcS = (const uint4*)(bfp + (unsigned)(b * 32) * 2048);
        bufS[0][tid]       = srcS[tid];
        bufS[0][tid + 256] = srcS[tid + 256];
        bufE[0][tid] = ((const uint4*)(xep + (unsigned)(b * 16) * 2048))[tid];
    }
    __syncthreads();

    int r = 0;   // global round counter (buffer parity)
    #pragma unroll 1
    for (int ph = 0; ph < 2; ++ph) {
        const int band = ph ? (15 - m) : m;
        const int q    = band * 32 + s * 4 + w;
        const int bq   = b * 512 + q;
        const int cmax = band;            // q>>5 == band by construction

        // ---- per-phase prologue ----
        float hqr[4][4];
        #pragma unroll
        for (int ht = 0; ht < 4; ++ht) {
            fx4 vh = *(const fx4*)(hq + bq * 64 + ht * 16 + quad * 4);
            #pragma unroll
            for (int rr = 0; rr < 4; ++rr) hqr[ht][rr] = vh[rr];
        }
        float xq[2][8];
        {
            const float* xp = x + bq * 64 + quad * 8;
            fx4 t0 = *(const fx4*)xp;
            fx4 t1 = *(const fx4*)(xp + 4);
            fx4 t2 = *(const fx4*)(xp + 32);
            fx4 t3 = *(const fx4*)(xp + 36);
            #pragma unroll
            for (int jj = 0; jj < 4; ++jj) {
                xq[0][jj] = t0[jj]; xq[0][4 + jj] = t1[jj];
                xq[1][jj] = t2[jj]; xq[1][4 + jj] = t3[jj];
            }
        }
        sx8 afrag[4][2];
        #pragma unroll
        for (int ht = 0; ht < 4; ++ht)
            #pragma unroll
            for (int hf = 0; hf < 2; ++hf) {
                const float* wp = wmf + (((ht * 2 + hf) * 64 + lane) << 3);
                fx4 w0 = *(const fx4*)wp;
                fx4 w1 = *(const fx4*)(wp + 4);
                sx8 a;
                #pragma unroll
                for (int jj = 0; jj < 4; ++jj) {
                    a[jj]     = (short)f2bf(w0[jj] * xq[hf][jj]);
                    a[4 + jj] = (short)f2bf(w1[jj] * xq[hf][4 + jj]);
                }
                afrag[ht][hf] = a;
            }

        fx4 eacc[4];
        #pragma unroll
        for (int nt = 0; nt < 4; ++nt) eacc[nt] = (fx4){0.f, 0.f, 0.f, 0.f};

        // ---- chunk loop ----
        for (int c = 0; c <= cmax; ++c, ++r) {
            // prefetch next round's chunk into registers
            uint4 st0, st1, stE;
            if (r < 16) {
                int nc = (r + 1 <= m) ? (r + 1) : (r - m);
                const uint4* srcS = (const uint4*)(bfp + (unsigned)(b * 32 + 2 * nc) * 2048);
                st0 = srcS[tid];
                st1 = srcS[tid + 256];
                stE = ((const uint4*)(xep + (unsigned)(b * 16 + nc) * 2048))[tid];
            }

            const unsigned short* ls = (const unsigned short*)&bufS[r & 1][0] + lane * 8;
            sx8 fa0 = *(const sx8*)(ls);
            sx8 fa1 = *(const sx8*)(ls + 512);
            sx8 fa2 = *(const sx8*)(ls + 1024);
            sx8 fa3 = *(const sx8*)(ls + 1536);
            sx8 fb0 = *(const sx8*)(ls + 2048);
            sx8 fb1 = *(const sx8*)(ls + 2560);
            sx8 fb2 = *(const sx8*)(ls + 3072);
            sx8 fb3 = *(const sx8*)(ls + 3584);

            fx4 accA[4], accB[4];
            #pragma unroll
            for (int ht = 0; ht < 4; ++ht) {
                accA[ht] = (fx4){hqr[ht][0], hqr[ht][1], hqr[ht][2], hqr[ht][3]};
                accB[ht] = accA[ht];
            }
            #pragma unroll
            for (int ht = 0; ht < 4; ++ht) {
                accA[ht] = __builtin_amdgcn_mfma_f32_16x16x32_bf16(afrag[ht][0], fa0, accA[ht], 0, 0, 0);
                accB[ht] = __builtin_amdgcn_mfma_f32_16x16x32_bf16(afrag[ht][0], fb0, accB[ht], 0, 0, 0);
            }
            #pragma unroll
            for (int ht = 0; ht < 4; ++ht) {
                accA[ht] = __builtin_amdgcn_mfma_f32_16x16x32_bf16(afrag[ht][1], fa1, accA[ht], 0, 0, 0);
                accB[ht] = __builtin_amdgcn_mfma_f32_16x16x32_bf16(afrag[ht][1], fb1, accB[ht], 0, 0, 0);
            }
            #pragma unroll
            for (int ht = 0; ht < 4; ++ht) {
                accA[ht] = __builtin_amdgcn_mfma_f32_16x16x32_bf16(oh[ht], (ht < 2) ? fa2 : fa3, accA[ht], 0, 0, 0);
                accB[ht] = __builtin_amdgcn_mfma_f32_16x16x32_bf16(oh[ht], (ht < 2) ? fb2 : fb3, accB[ht], 0, 0, 0);
            }

            // PReLU(z)=max(z, pa*z); W2 dot; quad-reduce
            float s0a = 0.f, s0b = 0.f, s1a = 0.f, s1b = 0.f;
            #pragma unroll
            for (int ht = 0; ht < 2; ++ht)
                #pragma unroll
                for (int rr = 0; rr < 4; ++rr) {
                    float za = accA[ht][rr], zb = accB[ht][rr];
                    s0a = fmaf(w2r[ht][rr], fmaxf(za, za * pa), s0a);
                    s1a = fmaf(w2r[ht][rr], fmaxf(zb, zb * pa), s1a);
                }
            #pragma unroll
            for (int ht = 2; ht < 4; ++ht)
                #pragma unroll
                for (int rr = 0; rr < 4; ++rr) {
                    float za = accA[ht][rr], zb = accB[ht][rr];
                    s0b = fmaf(w2r[ht][rr], fmaxf(za, za * pa), s0b);
                    s1b = fmaf(w2r[ht][rr], fmaxf(zb, zb * pa), s1b);
                }
            float s0 = s0a + s0b, s1 = s1a + s1b;
            s0 += __shfl_xor(s0, 16, 64);
            s0 += __shfl_xor(s0, 32, 64);
            s1 += __shfl_xor(s1, 16, 64);
            s1 += __shfl_xor(s1, 32, 64);
            int k0 = c * 32 + n;
            s0 = (k0 <= q)      ? s0 + b2v : 0.f;
            s1 = (k0 + 16 <= q) ? s1 + b2v : 0.f;

            // scores -> A-frag via per-wave LDS strip (same-wave order, no barrier)
            unsigned packed = (unsigned)f2bf(s0) | ((unsigned)f2bf(s1) << 16);
            if (quad == 0) strip[w][n] = packed;
            const unsigned* sp = &strip[w][(quad & 1) * 8];
            uint4 wv0 = *(const uint4*)sp;
            uint4 wv1 = *(const uint4*)(sp + 4);
            ix4 sw_;
            sw_[0] = (int)__builtin_amdgcn_perm(wv0.y, wv0.x, sel);
            sw_[1] = (int)__builtin_amdgcn_perm(wv0.w, wv0.z, sel);
            sw_[2] = (int)__builtin_amdgcn_perm(wv1.y, wv1.x, sel);
            sw_[3] = (int)__builtin_amdgcn_perm(wv1.w, wv1.z, sel);
            sx8 sfrag = __builtin_bit_cast(sx8, sw_);

            const unsigned short* le = (const unsigned short*)&bufE[r & 1][0] + lane * 8;
            sx8 e0 = *(const sx8*)(le);
            sx8 e1 = *(const sx8*)(le + 512);
            sx8 e2 = *(const sx8*)(le + 1024);
            sx8 e3 = *(const sx8*)(le + 1536);

            eacc[0] = __builtin_amdgcn_mfma_f32_16x16x32_bf16(sfrag, e0, eacc[0], 0, 0, 0);
            eacc[1] = __builtin_amdgcn_mfma_f32_16x16x32_bf16(sfrag, e1, eacc[1], 0, 0, 0);
            eacc[2] = __builtin_amdgcn_mfma_f32_16x16x32_bf16(sfrag, e2, eacc[2], 0, 0, 0);
            eacc[3] = __builtin_amdgcn_mfma_f32_16x16x32_bf16(sfrag, e3, eacc[3], 0, 0, 0);

            // commit next round's chunk
            if (r < 16) {
                bufS[(r + 1) & 1][tid]       = st0;
                bufS[(r + 1) & 1][tid + 256] = st1;
                bufE[(r + 1) & 1][tid]       = stE;
            }
            __syncthreads();
        }

        // all m-rows identical; lane's d = quad*16 + n = lane
        float ov = eacc[0][0];
        if (quad == 1) ov = eacc[1][0];
        if (quad == 2) ov = eacc[2][0];
        if (quad == 3) ov = eacc[3][0];
        out[bq * 64 + lane] = ov;
    }
}

extern "C" void kernel_launch(void* const* d_in, const int* in_sizes, int n_in,
                              void* d_out, int out_size, void* d_ws, size_t ws_size,
                              hipStream_t stream) {
    const float* x   = (const float*)d_in[1];
    const float* vmk = (const float*)d_in[2];
    const float* W1  = (const float*)d_in[3];
    const float* b1  = (const float*)d_in[4];
    const float* pa  = (const float*)d_in[5];
    const float* W2  = (const float*)d_in[6];
    const float* b2  = (const float*)d_in[7];
    float* ws  = (float*)d_ws;
    float* out = (float*)d_out;

    hipLaunchKernelGGL(prep, dim3(NB * NN / 4), dim3(256), 0, stream,
                       x, vmk, W1, b1, ws);
    hipLaunchKernelGGL(k2_main, dim3(NB * 64), dim3(256), 0, stream,
                       x, pa, W2, b2, ws, out);
}

// Round 9
// 102.573 us; speedup vs baseline: 1.1881x; 1.0052x over previous
//
#include <hip/hip_runtime.h>

// DIN encoder. B=8, N=512, D=64, H=64. Two launches:
//   prep   — weight transforms, hq, hk-scatter, X B-frags, enc-X B-frags
//   k2_main— 512 uniform blocks × 4 waves; band pair (m, 15-m) phases;
//            TWO 32-key chunks per round -> 9 barrier rounds (R8 had 17;
//            R8 lesson: main is round-latency x sequential-rounds bound).
// R3 lesson: tight VGPR caps -> scratch spill (FETCH blowup signature).
// (256,2) allows 256 VGPR/wave — safe.
#define NB 8
#define NN 512

// ws layout (float offsets)
#define WS_WMF 0        // Wm A-frag-major fp32 [8 slot][64 lane][8]          4096
#define WS_HQ  4096     // hq fp32 [B*N][64]                                262144
#define WS_BF  266240   // B-frags bf16 [B][32 t][4 c][64 lane][8]   (262144 fl)
#define WS_XE  528384   // enc-X bf16 [B][16 c32][4 nt][64 lane][8]  (131072 fl)

typedef float fx4 __attribute__((ext_vector_type(4)));
typedef short sx8 __attribute__((ext_vector_type(8)));
typedef int   ix4 __attribute__((ext_vector_type(4)));

static __device__ inline unsigned short f2bf(float f) {
    unsigned u = __float_as_uint(f);
    return (unsigned short)((u + 0x7FFFu + ((u >> 16) & 1u)) >> 16);  // RNE
}

// ---------------- fused prep ----------------
__global__ __launch_bounds__(256) void prep(const float* __restrict__ x,
                                            const float* __restrict__ vm,
                                            const float* __restrict__ W1,
                                            const float* __restrict__ b1,
                                            float* __restrict__ ws) {
    // R9: weights transposed to [h][d], stride 68 floats (16B aligned,
    // bank pattern == standard b128) -> dot loop reads b128, not b32.
    __shared__ float lwq[64 * 68];   // (Wq+Wd)  [h][d]
    __shared__ float lwk[64 * 68];   // (Wk-Wd)  [h][d]
    __shared__ float xs[256];
    const int t = threadIdx.x;
    const int blk = blockIdx.x;

    {
        int d = t & 63, hb = t >> 6;
        #pragma unroll 4
        for (int i = 0; i < 16; ++i) {
            int h = i * 4 + hb;
            float a = W1[h * 256 + d];
            float bb = W1[h * 256 + 64 + d];
            float c = W1[h * 256 + 128 + d];
            lwq[h * 68 + d] = a + c;
            lwk[h * 68 + d] = bb - c;
        }
    }
    const int r0 = blk * 4;
    xs[t] = x[r0 * 64 + t];
    __syncthreads();

    // hq + hk for this block's 4 rows (row = wave, h = lane)
    {
        int r = t >> 6, h = t & 63;
        const fx4* xr  = (const fx4*)(xs + r * 64);     // wave-uniform: broadcast
        const fx4* wqv = (const fx4*)(lwq + h * 68);
        const fx4* wkv = (const fx4*)(lwk + h * 68);
        float aq = b1[h], ak = 0.f;
        #pragma unroll
        for (int dd = 0; dd < 16; ++dd) {
            fx4 xv = xr[dd];
            fx4 wq = wqv[dd];
            fx4 wk = wkv[dd];
            aq = fmaf(xv[0], wq[0], aq); aq = fmaf(xv[1], wq[1], aq);
            aq = fmaf(xv[2], wq[2], aq); aq = fmaf(xv[3], wq[3], aq);
            ak = fmaf(xv[0], wk[0], ak); ak = fmaf(xv[1], wk[1], ak);
            ak = fmaf(xv[2], wk[2], ak); ak = fmaf(xv[3], wk[3], ak);
        }
        int row = r0 + r;
        (ws + WS_HQ)[row * 64 + h] = aq;
        // scatter hk into B-frag chunk c=2+(h>>5)
        unsigned short* bfp = (unsigned short*)(ws + WS_BF);
        int bb = row >> 9, k = row & 511;
        int tt = k >> 4, nn = k & 15;
        int c = 2 + (h >> 5);
        int qd = (h >> 3) & 3, j = h & 7;
        int ln = qd * 16 + nn;
        bfp[((((bb * 32 + tt) * 4 + c) * 64 + ln) << 3) + j] = f2bf(ak);
    }

    if (blk < 256) {
        int b = blk >> 5, t5 = blk & 31;
        // X -> BF chunks 0/1
        if (t < 128) {
            unsigned short* bfp = (unsigned short*)(ws + WS_BF);
            int c = t >> 6, L = t & 63;
            int nn = L & 15, qd = L >> 4;
            const float* src = x + ((b * 512 + t5 * 16 + nn) * 64 + c * 32 + qd * 8);
            fx4 v0 = *(const fx4*)src;
            fx4 v1 = *(const fx4*)(src + 4);
            uint4 o;
            o.x = (unsigned)f2bf(v0[0]) | ((unsigned)f2bf(v0[1]) << 16);
            o.y = (unsigned)f2bf(v0[2]) | ((unsigned)f2bf(v0[3]) << 16);
            o.z = (unsigned)f2bf(v1[0]) | ((unsigned)f2bf(v1[1]) << 16);
            o.w = (unsigned)f2bf(v1[2]) | ((unsigned)f2bf(v1[3]) << 16);
            *(uint4*)(bfp + ((((b * 32 + t5) * 4 + c) * 64 + L) << 3)) = o;
        }
        // masked X -> enc B-frags (XE)
        {
            unsigned short* xep = (unsigned short*)(ws + WS_XE);
            int c32 = t5 >> 1, half = t5 & 1;
            int nt = t >> 6, r = t & 63;
            int L = half * 32 + (r & 31);
            int j0 = (r >> 5) * 4;
            int quad = L >> 4, nn = L & 15;
            unsigned short u[4];
            #pragma unroll
            for (int i = 0; i < 4; ++i) {
                int key = c32 * 32 + quad * 8 + j0 + i;
                float v = x[(b * 512 + key) * 64 + nt * 16 + nn] * vm[b * 512 + key];
                u[i] = f2bf(v);
            }
            uint2 o;
            o.x = (unsigned)u[0] | ((unsigned)u[1] << 16);
            o.y = (unsigned)u[2] | ((unsigned)u[3] << 16);
            *(uint2*)(xep + (((((b * 16 + c32) * 4 + nt) * 64 + L) << 3) + j0)) = o;
        }
    } else if (blk < 258) {
        // Wm A-fragment-major
        float* wmf = ws + WS_WMF;
        int e = (blk - 256) * 256 + t;       // 0..511
        int slot = e >> 6, lane = e & 63;
        int ht = slot >> 1, hf = slot & 1;
        int mm = lane & 15, qd = lane >> 4;
        int h = ht * 16 + mm;
        int dbase = hf * 32 + qd * 8;
        #pragma unroll
        for (int j = 0; j < 8; ++j)
            wmf[e * 8 + j] = W1[h * 256 + 192 + dbase + j];
    }
}

// ------- main: 9 uniform dual-chunk rounds; band m then band 15-m -------
__global__ __launch_bounds__(256, 2) void k2_main(const float* __restrict__ x,
                                                  const float* __restrict__ prelu_a,
                                                  const float* __restrict__ W2,
                                                  const float* __restrict__ b2,
                                                  const float* __restrict__ ws,
                                                  float* __restrict__ out) {
    const int tid  = threadIdx.x;
    const int lane = tid & 63;
    const int w    = tid >> 6;            // 0..3
    const int blk  = blockIdx.x;
    const int b    = blk >> 6;
    const int rest = blk & 63;
    const int m    = rest >> 3;           // 0..7: band pair (m, 15-m)
    const int s    = rest & 7;            // 4-query slice within band
    const int n    = lane & 15, quad = lane >> 4;
    const int RA   = (m + 2) >> 1;        // phase-A rounds; RB = 9-RA

    const float* wmf = ws + WS_WMF;
    const float* hq  = ws + WS_HQ;
    const unsigned short* bfp = (const unsigned short*)(ws + WS_BF);
    const unsigned short* xep = (const unsigned short*)(ws + WS_XE);

    const float pa  = prelu_a[0];
    const float b2v = b2[0];

    __shared__ uint4 bufS[2][2][512];     // 2 buf x 2 chunk-slots x 8 KB
    __shared__ uint4 bufE[2][2][256];     // 2 buf x 2 chunk-slots x 4 KB
    __shared__ unsigned strip[4][2][16];  // per-wave, per-sub score strip

    // phase-independent: W2 (fx4), one-hot, perm sel
    fx4 w2v[4];
    #pragma unroll
    for (int ht = 0; ht < 4; ++ht)
        w2v[ht] = *(const fx4*)(W2 + ht * 16 + quad * 4);
    sx8 oh[4];
    #pragma unroll
    for (int ht = 0; ht < 4; ++ht) {
        sx8 a;
        #pragma unroll
        for (int jj = 0; jj < 8; ++jj) {
            int hp = (ht >> 1) * 32 + quad * 8 + jj;
            a[jj] = (hp == ht * 16 + n) ? (short)0x3F80 : (short)0;
        }
        oh[ht] = a;
    }
    const unsigned sel = (quad < 2) ? 0x05040100u : 0x07060302u;

    // stage round 0 (phase A chunks 0 and min(1,m))
    {
        int c1i = (m >= 1) ? 1 : 0;
        const uint4* sS0 = (const uint4*)(bfp + (unsigned)(b * 32) * 2048);
        const uint4* sS1 = (const uint4*)(bfp + (unsigned)(b * 32 + 2 * c1i) * 2048);
        bufS[0][0][tid] = sS0[tid]; bufS[0][0][tid + 256] = sS0[tid + 256];
        bufS[0][1][tid] = sS1[tid]; bufS[0][1][tid + 256] = sS1[tid + 256];
        bufE[0][0][tid] = ((const uint4*)(xep + (unsigned)(b * 16) * 2048))[tid];
        bufE[0][1][tid] = ((const uint4*)(xep + (unsigned)(b * 16 + c1i) * 2048))[tid];
    }
    __syncthreads();

    int r = 0;   // global round counter (buffer parity)
    #pragma unroll 1
    for (int ph = 0; ph < 2; ++ph) {
        const int band   = ph ? (15 - m) : m;
        const int q      = band * 32 + s * 4 + w;
        const int bq     = b * 512 + q;
        const int rounds = ph ? (9 - RA) : RA;

        // ---- per-phase prologue ----
        fx4 hqv[4];
        #pragma unroll
        for (int ht = 0; ht < 4; ++ht)
            hqv[ht] = *(const fx4*)(hq + bq * 64 + ht * 16 + quad * 4);
        float xq[2][8];
        {
            const float* xp = x + bq * 64 + quad * 8;
            fx4 t0 = *(const fx4*)xp;
            fx4 t1 = *(const fx4*)(xp + 4);
            fx4 t2 = *(const fx4*)(xp + 32);
            fx4 t3 = *(const fx4*)(xp + 36);
            #pragma unroll
            for (int jj = 0; jj < 4; ++jj) {
                xq[0][jj] = t0[jj]; xq[0][4 + jj] = t1[jj];
                xq[1][jj] = t2[jj]; xq[1][4 + jj] = t3[jj];
            }
        }
        sx8 afrag[4][2];
        #pragma unroll
        for (int ht = 0; ht < 4; ++ht)
            #pragma unroll
            for (int hf = 0; hf < 2; ++hf) {
                const float* wp = wmf + (((ht * 2 + hf) * 64 + lane) << 3);
                fx4 w0 = *(const fx4*)wp;
                fx4 w1 = *(const fx4*)(wp + 4);
                sx8 a;
                #pragma unroll
                for (int jj = 0; jj < 4; ++jj) {
                    a[jj]     = (short)f2bf(w0[jj] * xq[hf][jj]);
                    a[4 + jj] = (short)f2bf(w1[jj] * xq[hf][4 + jj]);
                }
                afrag[ht][hf] = a;
            }

        fx4 eacc[4];
        #pragma unroll
        for (int nt = 0; nt < 4; ++nt) eacc[nt] = (fx4){0.f, 0.f, 0.f, 0.f};

        // one 32-key chunk; parity selects buffer, sub selects slot
        auto do_chunk = [&](int c, int sub, int parity) {
            const unsigned short* ls = (const unsigned short*)&bufS[parity][sub][0] + lane * 8;
            sx8 fa0 = *(const sx8*)(ls);
            sx8 fa1 = *(const sx8*)(ls + 512);
            sx8 fa2 = *(const sx8*)(ls + 1024);
            sx8 fa3 = *(const sx8*)(ls + 1536);
            sx8 fb0 = *(const sx8*)(ls + 2048);
            sx8 fb1 = *(const sx8*)(ls + 2560);
            sx8 fb2 = *(const sx8*)(ls + 3072);
            sx8 fb3 = *(const sx8*)(ls + 3584);

            fx4 accA[4], accB[4];
            #pragma unroll
            for (int ht = 0; ht < 4; ++ht) { accA[ht] = hqv[ht]; accB[ht] = hqv[ht]; }
            #pragma unroll
            for (int ht = 0; ht < 4; ++ht) {
                accA[ht] = __builtin_amdgcn_mfma_f32_16x16x32_bf16(afrag[ht][0], fa0, accA[ht], 0, 0, 0);
                accB[ht] = __builtin_amdgcn_mfma_f32_16x16x32_bf16(afrag[ht][0], fb0, accB[ht], 0, 0, 0);
            }
            #pragma unroll
            for (int ht = 0; ht < 4; ++ht) {
                accA[ht] = __builtin_amdgcn_mfma_f32_16x16x32_bf16(afrag[ht][1], fa1, accA[ht], 0, 0, 0);
                accB[ht] = __builtin_amdgcn_mfma_f32_16x16x32_bf16(afrag[ht][1], fb1, accB[ht], 0, 0, 0);
            }
            #pragma unroll
            for (int ht = 0; ht < 4; ++ht) {
                accA[ht] = __builtin_amdgcn_mfma_f32_16x16x32_bf16(oh[ht], (ht < 2) ? fa2 : fa3, accA[ht], 0, 0, 0);
                accB[ht] = __builtin_amdgcn_mfma_f32_16x16x32_bf16(oh[ht], (ht < 2) ? fb2 : fb3, accB[ht], 0, 0, 0);
            }

            // PReLU(z)=max(z, pa*z); W2 dot as fx4 (packed fp32 ops)
            fx4 s0v = (fx4){0.f, 0.f, 0.f, 0.f};
            fx4 s1v = (fx4){0.f, 0.f, 0.f, 0.f};
            #pragma unroll
            for (int ht = 0; ht < 4; ++ht) {
                fx4 za = accA[ht], zb = accB[ht];
                fx4 ta = __builtin_elementwise_max(za, za * pa);
                fx4 tb = __builtin_elementwise_max(zb, zb * pa);
                s0v = ta * w2v[ht] + s0v;
                s1v = tb * w2v[ht] + s1v;
            }
            float s0 = (s0v[0] + s0v[1]) + (s0v[2] + s0v[3]);
            float s1 = (s1v[0] + s1v[1]) + (s1v[2] + s1v[3]);
            s0 += __shfl_xor(s0, 16, 64);
            s0 += __shfl_xor(s0, 32, 64);
            s1 += __shfl_xor(s1, 16, 64);
            s1 += __shfl_xor(s1, 32, 64);
            int k0 = c * 32 + n;
            s0 = (k0 <= q)      ? s0 + b2v : 0.f;
            s1 = (k0 + 16 <= q) ? s1 + b2v : 0.f;

            // scores -> A-frag via per-wave LDS strip (in-wave order)
            unsigned packed = (unsigned)f2bf(s0) | ((unsigned)f2bf(s1) << 16);
            if (quad == 0) strip[w][sub][n] = packed;
            const unsigned* sp = &strip[w][sub][(quad & 1) * 8];
            uint4 wv0 = *(const uint4*)sp;
            uint4 wv1 = *(const uint4*)(sp + 4);
            ix4 sw_;
            sw_[0] = (int)__builtin_amdgcn_perm(wv0.y, wv0.x, sel);
            sw_[1] = (int)__builtin_amdgcn_perm(wv0.w, wv0.z, sel);
            sw_[2] = (int)__builtin_amdgcn_perm(wv1.y, wv1.x, sel);
            sw_[3] = (int)__builtin_amdgcn_perm(wv1.w, wv1.z, sel);
            sx8 sfrag = __builtin_bit_cast(sx8, sw_);

            const unsigned short* le = (const unsigned short*)&bufE[parity][sub][0] + lane * 8;
            sx8 e0 = *(const sx8*)(le);
            sx8 e1 = *(const sx8*)(le + 512);
            sx8 e2 = *(const sx8*)(le + 1024);
            sx8 e3 = *(const sx8*)(le + 1536);

            eacc[0] = __builtin_amdgcn_mfma_f32_16x16x32_bf16(sfrag, e0, eacc[0], 0, 0, 0);
            eacc[1] = __builtin_amdgcn_mfma_f32_16x16x32_bf16(sfrag, e1, eacc[1], 0, 0, 0);
            eacc[2] = __builtin_amdgcn_mfma_f32_16x16x32_bf16(sfrag, e2, eacc[2], 0, 0, 0);
            eacc[3] = __builtin_amdgcn_mfma_f32_16x16x32_bf16(sfrag, e3, eacc[3], 0, 0, 0);
        };

        #pragma unroll 1
        for (int i = 0; i < rounds; ++i, ++r) {
            // prefetch next round's two chunks into registers
            uint4 st0, st1, st2, st3, stE0, stE1;
            if (r < 8) {
                int nr = r + 1, c0n, c1n;
                if (nr < RA) {
                    c0n = 2 * nr; c1n = (2 * nr + 1 <= m) ? 2 * nr + 1 : m;
                } else {
                    int jj = nr - RA, cb = 15 - m;
                    c0n = 2 * jj; c1n = (2 * jj + 1 <= cb) ? 2 * jj + 1 : cb;
                }
                const uint4* sS0 = (const uint4*)(bfp + (unsigned)(b * 32 + 2 * c0n) * 2048);
                const uint4* sS1 = (const uint4*)(bfp + (unsigned)(b * 32 + 2 * c1n) * 2048);
                st0 = sS0[tid]; st1 = sS0[tid + 256];
                st2 = sS1[tid]; st3 = sS1[tid + 256];
                stE0 = ((const uint4*)(xep + (unsigned)(b * 16 + c0n) * 2048))[tid];
                stE1 = ((const uint4*)(xep + (unsigned)(b * 16 + c1n) * 2048))[tid];
            }

            do_chunk(2 * i, 0, r & 1);
            if (2 * i + 1 <= band) do_chunk(2 * i + 1, 1, r & 1);

            if (r < 8) {
                int p2 = (r + 1) & 1;
                bufS[p2][0][tid] = st0; bufS[p2][0][tid + 256] = st1;
                bufS[p2][1][tid] = st2; bufS[p2][1][tid + 256] = st3;
                bufE[p2][0][tid] = stE0; bufE[p2][1][tid] = stE1;
            }
            __syncthreads();
        }

        // all m-rows identical; lane's d = quad*16 + n = lane
        float ov = eacc[0][0];
        if (quad == 1) ov = eacc[1][0];
        if (quad == 2) ov = eacc[2][0];
        if (quad == 3) ov = eacc[3][0];
        out[bq * 64 + lane] = ov;
    }
}

extern "C" void kernel_launch(void* const* d_in, const int* in_sizes, int n_in,
                              void* d_out, int out_size, void* d_ws, size_t ws_size,
                              hipStream_t stream) {
    const float* x   = (const float*)d_in[1];
    const float* vmk = (const float*)d_in[2];
    const float* W1  = (const float*)d_in[3];
    const float* b1  = (const float*)d_in[4];
    const float* pa  = (const float*)d_in[5];
    const float* W2  = (const float*)d_in[6];
    const float* b2  = (const float*)d_in[7];
    float* ws  = (float*)d_ws;
    float* out = (float*)d_out;

    hipLaunchKernelGGL(prep, dim3(NB * NN / 4), dim3(256), 0, stream,
                       x, vmk, W1, b1, ws);
    hipLaunchKernelGGL(k2_main, dim3(NB * 64), dim3(256), 0, stream,
                       x, pa, W2, b2, ws, out);
}

// Round 10
// 99.262 us; speedup vs baseline: 1.2278x; 1.0334x over previous
//
#include <hip/hip_runtime.h>

// DIN encoder. B=8, N=512, D=64, H=64. Two launches:
//   prep   — weight transforms, hq, hk-scatter, X B-frags, enc-X B-frags
//   k2_main— 1024 blocks × 4 waves; block = (b, band, slice): 4 queries of
//            ONE 32-aligned band, rounds = band+1, bands launched in
//            descending order (heavy first, short backfill the drain).
// R8/R9 lesson: 512-block grids were GRID-limited to 2 blocks/CU (8
//   wave-slots) while resources allow 4 blocks/CU; serial chunk-chain
//   latency × chunks-per-slot fit all three datapoints. R10 doubles the
//   independent chains per SIMD (4-way) with zero idle waves.
// R3 lesson: tight VGPR caps -> scratch spill (FETCH blowup). Keep (256,2);
//   occupancy comes from actual VGPR (~108 -> 4 waves/SIMD), not the bound.
#define NB 8
#define NN 512

// ws layout (float offsets)
#define WS_WMF 0        // Wm A-frag-major fp32 [8 slot][64 lane][8]          4096
#define WS_HQ  4096     // hq fp32 [B*N][64]                                262144
#define WS_BF  266240   // B-frags bf16 [B][32 t][4 c][64 lane][8]   (262144 fl)
#define WS_XE  528384   // enc-X bf16 [B][16 c32][4 nt][64 lane][8]  (131072 fl)

typedef float fx4 __attribute__((ext_vector_type(4)));
typedef short sx8 __attribute__((ext_vector_type(8)));
typedef int   ix4 __attribute__((ext_vector_type(4)));

static __device__ inline unsigned short f2bf(float f) {
    unsigned u = __float_as_uint(f);
    return (unsigned short)((u + 0x7FFFu + ((u >> 16) & 1u)) >> 16);  // RNE
}

// ---------------- fused prep ----------------
__global__ __launch_bounds__(256) void prep(const float* __restrict__ x,
                                            const float* __restrict__ vm,
                                            const float* __restrict__ W1,
                                            const float* __restrict__ b1,
                                            float* __restrict__ ws) {
    __shared__ float lwq[64 * 68];   // (Wq+Wd)  [h][d], stride 68 (16B-aligned)
    __shared__ float lwk[64 * 68];   // (Wk-Wd)  [h][d]
    __shared__ float xs[256];
    const int t = threadIdx.x;
    const int blk = blockIdx.x;

    {
        int d = t & 63, hb = t >> 6;
        #pragma unroll 4
        for (int i = 0; i < 16; ++i) {
            int h = i * 4 + hb;
            float a = W1[h * 256 + d];
            float bb = W1[h * 256 + 64 + d];
            float c = W1[h * 256 + 128 + d];
            lwq[h * 68 + d] = a + c;
            lwk[h * 68 + d] = bb - c;
        }
    }
    const int r0 = blk * 4;
    xs[t] = x[r0 * 64 + t];
    __syncthreads();

    // hq + hk for this block's 4 rows (row = wave, h = lane), b128 reads
    {
        int r = t >> 6, h = t & 63;
        const fx4* xr  = (const fx4*)(xs + r * 64);
        const fx4* wqv = (const fx4*)(lwq + h * 68);
        const fx4* wkv = (const fx4*)(lwk + h * 68);
        float aq = b1[h], ak = 0.f;
        #pragma unroll
        for (int dd = 0; dd < 16; ++dd) {
            fx4 xv = xr[dd];
            fx4 wq = wqv[dd];
            fx4 wk = wkv[dd];
            aq = fmaf(xv[0], wq[0], aq); aq = fmaf(xv[1], wq[1], aq);
            aq = fmaf(xv[2], wq[2], aq); aq = fmaf(xv[3], wq[3], aq);
            ak = fmaf(xv[0], wk[0], ak); ak = fmaf(xv[1], wk[1], ak);
            ak = fmaf(xv[2], wk[2], ak); ak = fmaf(xv[3], wk[3], ak);
        }
        int row = r0 + r;
        (ws + WS_HQ)[row * 64 + h] = aq;
        // scatter hk into B-frag chunk c=2+(h>>5)
        unsigned short* bfp = (unsigned short*)(ws + WS_BF);
        int bb = row >> 9, k = row & 511;
        int tt = k >> 4, nn = k & 15;
        int c = 2 + (h >> 5);
        int qd = (h >> 3) & 3, j = h & 7;
        int ln = qd * 16 + nn;
        bfp[((((bb * 32 + tt) * 4 + c) * 64 + ln) << 3) + j] = f2bf(ak);
    }

    if (blk < 256) {
        int b = blk >> 5, t5 = blk & 31;
        // X -> BF chunks 0/1
        if (t < 128) {
            unsigned short* bfp = (unsigned short*)(ws + WS_BF);
            int c = t >> 6, L = t & 63;
            int nn = L & 15, qd = L >> 4;
            const float* src = x + ((b * 512 + t5 * 16 + nn) * 64 + c * 32 + qd * 8);
            fx4 v0 = *(const fx4*)src;
            fx4 v1 = *(const fx4*)(src + 4);
            uint4 o;
            o.x = (unsigned)f2bf(v0[0]) | ((unsigned)f2bf(v0[1]) << 16);
            o.y = (unsigned)f2bf(v0[2]) | ((unsigned)f2bf(v0[3]) << 16);
            o.z = (unsigned)f2bf(v1[0]) | ((unsigned)f2bf(v1[1]) << 16);
            o.w = (unsigned)f2bf(v1[2]) | ((unsigned)f2bf(v1[3]) << 16);
            *(uint4*)(bfp + ((((b * 32 + t5) * 4 + c) * 64 + L) << 3)) = o;
        }
        // masked X -> enc B-frags (XE)
        {
            unsigned short* xep = (unsigned short*)(ws + WS_XE);
            int c32 = t5 >> 1, half = t5 & 1;
            int nt = t >> 6, r = t & 63;
            int L = half * 32 + (r & 31);
            int j0 = (r >> 5) * 4;
            int quad = L >> 4, nn = L & 15;
            unsigned short u[4];
            #pragma unroll
            for (int i = 0; i < 4; ++i) {
                int key = c32 * 32 + quad * 8 + j0 + i;
                float v = x[(b * 512 + key) * 64 + nt * 16 + nn] * vm[b * 512 + key];
                u[i] = f2bf(v);
            }
            uint2 o;
            o.x = (unsigned)u[0] | ((unsigned)u[1] << 16);
            o.y = (unsigned)u[2] | ((unsigned)u[3] << 16);
            *(uint2*)(xep + (((((b * 16 + c32) * 4 + nt) * 64 + L) << 3) + j0)) = o;
        }
    } else if (blk < 258) {
        // Wm A-fragment-major
        float* wmf = ws + WS_WMF;
        int e = (blk - 256) * 256 + t;       // 0..511
        int slot = e >> 6, lane = e & 63;
        int ht = slot >> 1, hf = slot & 1;
        int mm = lane & 15, qd = lane >> 4;
        int h = ht * 16 + mm;
        int dbase = hf * 32 + qd * 8;
        #pragma unroll
        for (int j = 0; j < 8; ++j)
            wmf[e * 8 + j] = W1[h * 256 + 192 + dbase + j];
    }
}

// ------- main: 1024 blocks, one band each, bands descending -------
__global__ __launch_bounds__(256, 2) void k2_main(const float* __restrict__ x,
                                                  const float* __restrict__ prelu_a,
                                                  const float* __restrict__ W2,
                                                  const float* __restrict__ b2,
                                                  const float* __restrict__ ws,
                                                  float* __restrict__ out) {
    const int tid  = threadIdx.x;
    const int lane = tid & 63;
    const int w    = tid >> 6;            // 0..3
    const int blk  = blockIdx.x;
    const int band = 15 - (blk >> 6);     // heavy bands dispatch first
    const int rest = blk & 63;
    const int b    = rest >> 3;
    const int s    = rest & 7;            // 4-query slice within band
    const int n    = lane & 15, quad = lane >> 4;
    const int q    = band * 32 + s * 4 + w;
    const int bq   = b * 512 + q;
    const int cmax = band;                // q>>5 == band by construction

    const float* wmf = ws + WS_WMF;
    const float* hq  = ws + WS_HQ;
    const unsigned short* bfp = (const unsigned short*)(ws + WS_BF);
    const unsigned short* xep = (const unsigned short*)(ws + WS_XE);

    const float pa  = prelu_a[0];
    const float b2v = b2[0];

    __shared__ uint4 bufS[2][512];     // score frags: 8 KB per buffer
    __shared__ uint4 bufE[2][256];     // enc-X frags: 4 KB per buffer
    __shared__ unsigned strip[4][16];  // per-wave packed score strip

    // W2 (fx4), one-hot, perm sel
    fx4 w2v[4];
    #pragma unroll
    for (int ht = 0; ht < 4; ++ht)
        w2v[ht] = *(const fx4*)(W2 + ht * 16 + quad * 4);
    sx8 oh[4];
    #pragma unroll
    for (int ht = 0; ht < 4; ++ht) {
        sx8 a;
        #pragma unroll
        for (int jj = 0; jj < 8; ++jj) {
            int hp = (ht >> 1) * 32 + quad * 8 + jj;
            a[jj] = (hp == ht * 16 + n) ? (short)0x3F80 : (short)0;
        }
        oh[ht] = a;
    }
    const unsigned sel = (quad < 2) ? 0x05040100u : 0x07060302u;

    // per-query prologue
    fx4 hqv[4];
    #pragma unroll
    for (int ht = 0; ht < 4; ++ht)
        hqv[ht] = *(const fx4*)(hq + bq * 64 + ht * 16 + quad * 4);
    float xq[2][8];
    {
        const float* xp = x + bq * 64 + quad * 8;
        fx4 t0 = *(const fx4*)xp;
        fx4 t1 = *(const fx4*)(xp + 4);
        fx4 t2 = *(const fx4*)(xp + 32);
        fx4 t3 = *(const fx4*)(xp + 36);
        #pragma unroll
        for (int jj = 0; jj < 4; ++jj) {
            xq[0][jj] = t0[jj]; xq[0][4 + jj] = t1[jj];
            xq[1][jj] = t2[jj]; xq[1][4 + jj] = t3[jj];
        }
    }
    sx8 afrag[4][2];
    #pragma unroll
    for (int ht = 0; ht < 4; ++ht)
        #pragma unroll
        for (int hf = 0; hf < 2; ++hf) {
            const float* wp = wmf + (((ht * 2 + hf) * 64 + lane) << 3);
            fx4 w0 = *(const fx4*)wp;
            fx4 w1 = *(const fx4*)(wp + 4);
            sx8 a;
            #pragma unroll
            for (int jj = 0; jj < 4; ++jj) {
                a[jj]     = (short)f2bf(w0[jj] * xq[hf][jj]);
                a[4 + jj] = (short)f2bf(w1[jj] * xq[hf][4 + jj]);
            }
            afrag[ht][hf] = a;
        }

    fx4 eacc[4];
    #pragma unroll
    for (int nt = 0; nt < 4; ++nt) eacc[nt] = (fx4){0.f, 0.f, 0.f, 0.f};

    // stage chunk 0
    {
        const uint4* sS = (const uint4*)(bfp + (unsigned)(b * 32) * 2048);
        bufS[0][tid]       = sS[tid];
        bufS[0][tid + 256] = sS[tid + 256];
        bufE[0][tid] = ((const uint4*)(xep + (unsigned)(b * 16) * 2048))[tid];
    }
    __syncthreads();

    #pragma unroll 1
    for (int c = 0; c <= cmax; ++c) {
        // prefetch next chunk into registers (hidden behind compute)
        uint4 st0, st1, stE;
        if (c < cmax) {
            const uint4* sS = (const uint4*)(bfp + (unsigned)(b * 32 + 2 * (c + 1)) * 2048);
            st0 = sS[tid];
            st1 = sS[tid + 256];
            stE = ((const uint4*)(xep + (unsigned)(b * 16 + c + 1) * 2048))[tid];
        }

        const int p = c & 1;
        const unsigned short* ls = (const unsigned short*)&bufS[p][0] + lane * 8;
        sx8 fa0 = *(const sx8*)(ls);
        sx8 fa1 = *(const sx8*)(ls + 512);
        sx8 fa2 = *(const sx8*)(ls + 1024);
        sx8 fa3 = *(const sx8*)(ls + 1536);
        sx8 fb0 = *(const sx8*)(ls + 2048);
        sx8 fb1 = *(const sx8*)(ls + 2560);
        sx8 fb2 = *(const sx8*)(ls + 3072);
        sx8 fb3 = *(const sx8*)(ls + 3584);

        fx4 accA[4], accB[4];
        #pragma unroll
        for (int ht = 0; ht < 4; ++ht) { accA[ht] = hqv[ht]; accB[ht] = hqv[ht]; }
        #pragma unroll
        for (int ht = 0; ht < 4; ++ht) {
            accA[ht] = __builtin_amdgcn_mfma_f32_16x16x32_bf16(afrag[ht][0], fa0, accA[ht], 0, 0, 0);
            accB[ht] = __builtin_amdgcn_mfma_f32_16x16x32_bf16(afrag[ht][0], fb0, accB[ht], 0, 0, 0);
        }
        #pragma unroll
        for (int ht = 0; ht < 4; ++ht) {
            accA[ht] = __builtin_amdgcn_mfma_f32_16x16x32_bf16(afrag[ht][1], fa1, accA[ht], 0, 0, 0);
            accB[ht] = __builtin_amdgcn_mfma_f32_16x16x32_bf16(afrag[ht][1], fb1, accB[ht], 0, 0, 0);
        }
        #pragma unroll
        for (int ht = 0; ht < 4; ++ht) {
            accA[ht] = __builtin_amdgcn_mfma_f32_16x16x32_bf16(oh[ht], (ht < 2) ? fa2 : fa3, accA[ht], 0, 0, 0);
            accB[ht] = __builtin_amdgcn_mfma_f32_16x16x32_bf16(oh[ht], (ht < 2) ? fb2 : fb3, accB[ht], 0, 0, 0);
        }

        // PReLU(z)=max(z, pa*z); W2 dot as fx4; quad-reduce
        fx4 s0v = (fx4){0.f, 0.f, 0.f, 0.f};
        fx4 s1v = (fx4){0.f, 0.f, 0.f, 0.f};
        #pragma unroll
        for (int ht = 0; ht < 4; ++ht) {
            fx4 za = accA[ht], zb = accB[ht];
            fx4 ta = __builtin_elementwise_max(za, za * pa);
            fx4 tb = __builtin_elementwise_max(zb, zb * pa);
            s0v = ta * w2v[ht] + s0v;
            s1v = tb * w2v[ht] + s1v;
        }
        float s0 = (s0v[0] + s0v[1]) + (s0v[2] + s0v[3]);
        float s1 = (s1v[0] + s1v[1]) + (s1v[2] + s1v[3]);
        s0 += __shfl_xor(s0, 16, 64);
        s0 += __shfl_xor(s0, 32, 64);
        s1 += __shfl_xor(s1, 16, 64);
        s1 += __shfl_xor(s1, 32, 64);
        int k0 = c * 32 + n;
        s0 = (k0 <= q)      ? s0 + b2v : 0.f;
        s1 = (k0 + 16 <= q) ? s1 + b2v : 0.f;

        // scores -> A-frag via per-wave LDS strip (in-wave order)
        unsigned packed = (unsigned)f2bf(s0) | ((unsigned)f2bf(s1) << 16);
        if (quad == 0) strip[w][n] = packed;
        const unsigned* sp = &strip[w][(quad & 1) * 8];
        uint4 wv0 = *(const uint4*)sp;
        uint4 wv1 = *(const uint4*)(sp + 4);
        ix4 sw_;
        sw_[0] = (int)__builtin_amdgcn_perm(wv0.y, wv0.x, sel);
        sw_[1] = (int)__builtin_amdgcn_perm(wv0.w, wv0.z, sel);
        sw_[2] = (int)__builtin_amdgcn_perm(wv1.y, wv1.x, sel);
        sw_[3] = (int)__builtin_amdgcn_perm(wv1.w, wv1.z, sel);
        sx8 sfrag = __builtin_bit_cast(sx8, sw_);

        const unsigned short* le = (const unsigned short*)&bufE[p][0] + lane * 8;
        sx8 e0 = *(const sx8*)(le);
        sx8 e1 = *(const sx8*)(le + 512);
        sx8 e2 = *(const sx8*)(le + 1024);
        sx8 e3 = *(const sx8*)(le + 1536);

        eacc[0] = __builtin_amdgcn_mfma_f32_16x16x32_bf16(sfrag, e0, eacc[0], 0, 0, 0);
        eacc[1] = __builtin_amdgcn_mfma_f32_16x16x32_bf16(sfrag, e1, eacc[1], 0, 0, 0);
        eacc[2] = __builtin_amdgcn_mfma_f32_16x16x32_bf16(sfrag, e2, eacc[2], 0, 0, 0);
        eacc[3] = __builtin_amdgcn_mfma_f32_16x16x32_bf16(sfrag, e3, eacc[3], 0, 0, 0);

        // commit next chunk
        if (c < cmax) {
            const int p2 = (c + 1) & 1;
            bufS[p2][tid]       = st0;
            bufS[p2][tid + 256] = st1;
            bufE[p2][tid]       = stE;
        }
        __syncthreads();
    }

    // all m-rows identical; lane's d = quad*16 + n = lane
    float ov = eacc[0][0];
    if (quad == 1) ov = eacc[1][0];
    if (quad == 2) ov = eacc[2][0];
    if (quad == 3) ov = eacc[3][0];
    out[bq * 64 + lane] = ov;
}

extern "C" void kernel_launch(void* const* d_in, const int* in_sizes, int n_in,
                              void* d_out, int out_size, void* d_ws, size_t ws_size,
                              hipStream_t stream) {
    const float* x   = (const float*)d_in[1];
    const float* vmk = (const float*)d_in[2];
    const float* W1  = (const float*)d_in[3];
    const float* b1  = (const float*)d_in[4];
    const float* pa  = (const float*)d_in[5];
    const float* W2  = (const float*)d_in[6];
    const float* b2  = (const float*)d_in[7];
    float* ws  = (float*)d_ws;
    float* out = (float*)d_out;

    hipLaunchKernelGGL(prep, dim3(NB * NN / 4), dim3(256), 0, stream,
                       x, vmk, W1, b1, ws);
    hipLaunchKernelGGL(k2_main, dim3(1024), dim3(256), 0, stream,
                       x, pa, W2, b2, ws, out);
}

// Round 11
// 98.038 us; speedup vs baseline: 1.2431x; 1.0125x over previous
//
#include <hip/hip_runtime.h>

// DIN encoder. B=8, N=512, D=64, H=64. Two launches:
//   prep   — weight transforms, hq, hk-scatter, X B-frags, enc-X B-frags
//   k2_main— 1024 blocks × 4 waves; block = (band via LUT, b, slice).
// R11: (a) band LUT balances per-CU round totals (every CU's 4 resident
//      blocks sum to 30 bands = 34 rounds; R10 had 40 vs 28 skew);
//      (b) global_load_lds async DMA staging (width 16) replaces the
//      register prefetch+ds_write commit: -12 VGPR, -12 LDS writes/round,
//      __syncthreads' vmcnt(0) drain provides ordering (m97 pattern).
// R3 lesson: tight VGPR caps -> scratch spill. Keep (256,2).
#define NB 8
#define NN 512

// ws layout (float offsets)
#define WS_WMF 0        // Wm A-frag-major fp32 [8 slot][64 lane][8]          4096
#define WS_HQ  4096     // hq fp32 [B*N][64]                                262144
#define WS_BF  266240   // B-frags bf16 [B][32 t][4 c][64 lane][8]   (262144 fl)
#define WS_XE  528384   // enc-X bf16 [B][16 c32][4 nt][64 lane][8]  (131072 fl)

typedef float fx4 __attribute__((ext_vector_type(4)));
typedef short sx8 __attribute__((ext_vector_type(8)));
typedef int   ix4 __attribute__((ext_vector_type(4)));

static __device__ inline unsigned short f2bf(float f) {
    unsigned u = __float_as_uint(f);
    return (unsigned short)((u + 0x7FFFu + ((u >> 16) & 1u)) >> 16);  // RNE
}

// async 16B/lane global -> LDS DMA (gfx950). Lanes must be contiguous:
// caller passes per-thread g/l with lane-consecutive 16B addresses.
static __device__ inline void async_cp16(const void* g, void* l) {
    __builtin_amdgcn_global_load_lds(
        (const __attribute__((address_space(1))) unsigned int*)g,
        (__attribute__((address_space(3))) unsigned int*)l, 16, 0, 0);
}

// ---------------- fused prep ----------------
__global__ __launch_bounds__(256) void prep(const float* __restrict__ x,
                                            const float* __restrict__ vm,
                                            const float* __restrict__ W1,
                                            const float* __restrict__ b1,
                                            float* __restrict__ ws) {
    __shared__ float lwq[64 * 68];   // (Wq+Wd)  [h][d], stride 68 (16B-aligned)
    __shared__ float lwk[64 * 68];   // (Wk-Wd)  [h][d]
    __shared__ float xs[256];
    const int t = threadIdx.x;
    const int blk = blockIdx.x;

    {
        int d = t & 63, hb = t >> 6;
        #pragma unroll 4
        for (int i = 0; i < 16; ++i) {
            int h = i * 4 + hb;
            float a = W1[h * 256 + d];
            float bb = W1[h * 256 + 64 + d];
            float c = W1[h * 256 + 128 + d];
            lwq[h * 68 + d] = a + c;
            lwk[h * 68 + d] = bb - c;
        }
    }
    const int r0 = blk * 4;
    xs[t] = x[r0 * 64 + t];
    __syncthreads();

    // hq + hk for this block's 4 rows (row = wave, h = lane), b128 reads
    {
        int r = t >> 6, h = t & 63;
        const fx4* xr  = (const fx4*)(xs + r * 64);
        const fx4* wqv = (const fx4*)(lwq + h * 68);
        const fx4* wkv = (const fx4*)(lwk + h * 68);
        float aq = b1[h], ak = 0.f;
        #pragma unroll
        for (int dd = 0; dd < 16; ++dd) {
            fx4 xv = xr[dd];
            fx4 wq = wqv[dd];
            fx4 wk = wkv[dd];
            aq = fmaf(xv[0], wq[0], aq); aq = fmaf(xv[1], wq[1], aq);
            aq = fmaf(xv[2], wq[2], aq); aq = fmaf(xv[3], wq[3], aq);
            ak = fmaf(xv[0], wk[0], ak); ak = fmaf(xv[1], wk[1], ak);
            ak = fmaf(xv[2], wk[2], ak); ak = fmaf(xv[3], wk[3], ak);
        }
        int row = r0 + r;
        (ws + WS_HQ)[row * 64 + h] = aq;
        // scatter hk into B-frag chunk c=2+(h>>5)
        unsigned short* bfp = (unsigned short*)(ws + WS_BF);
        int bb = row >> 9, k = row & 511;
        int tt = k >> 4, nn = k & 15;
        int c = 2 + (h >> 5);
        int qd = (h >> 3) & 3, j = h & 7;
        int ln = qd * 16 + nn;
        bfp[((((bb * 32 + tt) * 4 + c) * 64 + ln) << 3) + j] = f2bf(ak);
    }

    if (blk < 256) {
        int b = blk >> 5, t5 = blk & 31;
        // X -> BF chunks 0/1
        if (t < 128) {
            unsigned short* bfp = (unsigned short*)(ws + WS_BF);
            int c = t >> 6, L = t & 63;
            int nn = L & 15, qd = L >> 4;
            const float* src = x + ((b * 512 + t5 * 16 + nn) * 64 + c * 32 + qd * 8);
            fx4 v0 = *(const fx4*)src;
            fx4 v1 = *(const fx4*)(src + 4);
            uint4 o;
            o.x = (unsigned)f2bf(v0[0]) | ((unsigned)f2bf(v0[1]) << 16);
            o.y = (unsigned)f2bf(v0[2]) | ((unsigned)f2bf(v0[3]) << 16);
            o.z = (unsigned)f2bf(v1[0]) | ((unsigned)f2bf(v1[1]) << 16);
            o.w = (unsigned)f2bf(v1[2]) | ((unsigned)f2bf(v1[3]) << 16);
            *(uint4*)(bfp + ((((b * 32 + t5) * 4 + c) * 64 + L) << 3)) = o;
        }
        // masked X -> enc B-frags (XE)
        {
            unsigned short* xep = (unsigned short*)(ws + WS_XE);
            int c32 = t5 >> 1, half = t5 & 1;
            int nt = t >> 6, r = t & 63;
            int L = half * 32 + (r & 31);
            int j0 = (r >> 5) * 4;
            int quad = L >> 4, nn = L & 15;
            unsigned short u[4];
            #pragma unroll
            for (int i = 0; i < 4; ++i) {
                int key = c32 * 32 + quad * 8 + j0 + i;
                float v = x[(b * 512 + key) * 64 + nt * 16 + nn] * vm[b * 512 + key];
                u[i] = f2bf(v);
            }
            uint2 o;
            o.x = (unsigned)u[0] | ((unsigned)u[1] << 16);
            o.y = (unsigned)u[2] | ((unsigned)u[3] << 16);
            *(uint2*)(xep + (((((b * 16 + c32) * 4 + nt) * 64 + L) << 3) + j0)) = o;
        }
    } else if (blk < 258) {
        // Wm A-fragment-major
        float* wmf = ws + WS_WMF;
        int e = (blk - 256) * 256 + t;       // 0..511
        int slot = e >> 6, lane = e & 63;
        int ht = slot >> 1, hf = slot & 1;
        int mm = lane & 15, qd = lane >> 4;
        int h = ht * 16 + mm;
        int dbase = hf * 32 + qd * 8;
        #pragma unroll
        for (int j = 0; j < 8; ++j)
            wmf[e * 8 + j] = W1[h * 256 + 192 + dbase + j];
    }
}

// ------- main: 1024 blocks, band LUT balanced, async DMA staging -------
__global__ __launch_bounds__(256, 2) void k2_main(const float* __restrict__ x,
                                                  const float* __restrict__ prelu_a,
                                                  const float* __restrict__ W2,
                                                  const float* __restrict__ b2,
                                                  const float* __restrict__ ws,
                                                  float* __restrict__ out) {
    const int tid  = threadIdx.x;
    const int lane = tid & 63;
    const int w    = tid >> 6;            // 0..3
    const int blk  = blockIdx.x;
    // band LUT: columns {j, j+4, j+8, j+12} sum to 30 -> every CU's 4
    // resident blocks (stride-256 pattern) total 34 rounds. Heavy first.
    const int band = (int)((0x4501763298DCABEFULL >> ((blk >> 6) << 2)) & 0xF);
    const int rest = blk & 63;
    const int b    = rest >> 3;
    const int s    = rest & 7;            // 4-query slice within band
    const int n    = lane & 15, quad = lane >> 4;
    const int q    = band * 32 + s * 4 + w;
    const int bq   = b * 512 + q;
    const int cmax = band;                // q>>5 == band by construction

    const float* wmf = ws + WS_WMF;
    const float* hq  = ws + WS_HQ;
    const unsigned short* bfp = (const unsigned short*)(ws + WS_BF);
    const unsigned short* xep = (const unsigned short*)(ws + WS_XE);

    const float pa  = prelu_a[0];
    const float b2v = b2[0];

    __shared__ uint4 bufS[2][512];     // score frags: 8 KB per buffer
    __shared__ uint4 bufE[2][256];     // enc-X frags: 4 KB per buffer
    __shared__ unsigned strip[4][16];  // per-wave packed score strip

    // W2 (fx4), one-hot, perm sel
    fx4 w2v[4];
    #pragma unroll
    for (int ht = 0; ht < 4; ++ht)
        w2v[ht] = *(const fx4*)(W2 + ht * 16 + quad * 4);
    sx8 oh[4];
    #pragma unroll
    for (int ht = 0; ht < 4; ++ht) {
        sx8 a;
        #pragma unroll
        for (int jj = 0; jj < 8; ++jj) {
            int hp = (ht >> 1) * 32 + quad * 8 + jj;
            a[jj] = (hp == ht * 16 + n) ? (short)0x3F80 : (short)0;
        }
        oh[ht] = a;
    }
    const unsigned sel = (quad < 2) ? 0x05040100u : 0x07060302u;

    // per-query prologue
    fx4 hqv[4];
    #pragma unroll
    for (int ht = 0; ht < 4; ++ht)
        hqv[ht] = *(const fx4*)(hq + bq * 64 + ht * 16 + quad * 4);
    float xq[2][8];
    {
        const float* xp = x + bq * 64 + quad * 8;
        fx4 t0 = *(const fx4*)xp;
        fx4 t1 = *(const fx4*)(xp + 4);
        fx4 t2 = *(const fx4*)(xp + 32);
        fx4 t3 = *(const fx4*)(xp + 36);
        #pragma unroll
        for (int jj = 0; jj < 4; ++jj) {
            xq[0][jj] = t0[jj]; xq[0][4 + jj] = t1[jj];
            xq[1][jj] = t2[jj]; xq[1][4 + jj] = t3[jj];
        }
    }
    sx8 afrag[4][2];
    #pragma unroll
    for (int ht = 0; ht < 4; ++ht)
        #pragma unroll
        for (int hf = 0; hf < 2; ++hf) {
            const float* wp = wmf + (((ht * 2 + hf) * 64 + lane) << 3);
            fx4 w0 = *(const fx4*)wp;
            fx4 w1 = *(const fx4*)(wp + 4);
            sx8 a;
            #pragma unroll
            for (int jj = 0; jj < 4; ++jj) {
                a[jj]     = (short)f2bf(w0[jj] * xq[hf][jj]);
                a[4 + jj] = (short)f2bf(w1[jj] * xq[hf][4 + jj]);
            }
            afrag[ht][hf] = a;
        }

    fx4 eacc[4];
    #pragma unroll
    for (int nt = 0; nt < 4; ++nt) eacc[nt] = (fx4){0.f, 0.f, 0.f, 0.f};

    // stage chunk 0 via async DMA; __syncthreads drains vmcnt
    {
        const uint4* sS = (const uint4*)(bfp + (unsigned)(b * 32) * 2048);
        const uint4* sE = (const uint4*)(xep + (unsigned)(b * 16) * 2048);
        async_cp16(sS + tid,       &bufS[0][tid]);
        async_cp16(sS + tid + 256, &bufS[0][tid + 256]);
        async_cp16(sE + tid,       &bufE[0][tid]);
    }
    __syncthreads();

    #pragma unroll 1
    for (int c = 0; c <= cmax; ++c) {
        // async-stage next chunk into the back buffer (DMA, no VGPRs)
        if (c < cmax) {
            const int p2 = (c + 1) & 1;
            const uint4* sS = (const uint4*)(bfp + (unsigned)(b * 32 + 2 * (c + 1)) * 2048);
            const uint4* sE = (const uint4*)(xep + (unsigned)(b * 16 + c + 1) * 2048);
            async_cp16(sS + tid,       &bufS[p2][tid]);
            async_cp16(sS + tid + 256, &bufS[p2][tid + 256]);
            async_cp16(sE + tid,       &bufE[p2][tid]);
        }

        const int p = c & 1;
        const unsigned short* ls = (const unsigned short*)&bufS[p][0] + lane * 8;
        sx8 fa0 = *(const sx8*)(ls);
        sx8 fa1 = *(const sx8*)(ls + 512);
        sx8 fa2 = *(const sx8*)(ls + 1024);
        sx8 fa3 = *(const sx8*)(ls + 1536);
        sx8 fb0 = *(const sx8*)(ls + 2048);
        sx8 fb1 = *(const sx8*)(ls + 2560);
        sx8 fb2 = *(const sx8*)(ls + 3072);
        sx8 fb3 = *(const sx8*)(ls + 3584);

        fx4 accA[4], accB[4];
        #pragma unroll
        for (int ht = 0; ht < 4; ++ht) { accA[ht] = hqv[ht]; accB[ht] = hqv[ht]; }
        #pragma unroll
        for (int ht = 0; ht < 4; ++ht) {
            accA[ht] = __builtin_amdgcn_mfma_f32_16x16x32_bf16(afrag[ht][0], fa0, accA[ht], 0, 0, 0);
            accB[ht] = __builtin_amdgcn_mfma_f32_16x16x32_bf16(afrag[ht][0], fb0, accB[ht], 0, 0, 0);
        }
        #pragma unroll
        for (int ht = 0; ht < 4; ++ht) {
            accA[ht] = __builtin_amdgcn_mfma_f32_16x16x32_bf16(afrag[ht][1], fa1, accA[ht], 0, 0, 0);
            accB[ht] = __builtin_amdgcn_mfma_f32_16x16x32_bf16(afrag[ht][1], fb1, accB[ht], 0, 0, 0);
        }
        #pragma unroll
        for (int ht = 0; ht < 4; ++ht) {
            accA[ht] = __builtin_amdgcn_mfma_f32_16x16x32_bf16(oh[ht], (ht < 2) ? fa2 : fa3, accA[ht], 0, 0, 0);
            accB[ht] = __builtin_amdgcn_mfma_f32_16x16x32_bf16(oh[ht], (ht < 2) ? fb2 : fb3, accB[ht], 0, 0, 0);
        }

        // PReLU(z)=max(z, pa*z); W2 dot as fx4; quad-reduce
        fx4 s0v = (fx4){0.f, 0.f, 0.f, 0.f};
        fx4 s1v = (fx4){0.f, 0.f, 0.f, 0.f};
        #pragma unroll
        for (int ht = 0; ht < 4; ++ht) {
            fx4 za = accA[ht], zb = accB[ht];
            fx4 ta = __builtin_elementwise_max(za, za * pa);
            fx4 tb = __builtin_elementwise_max(zb, zb * pa);
            s0v = ta * w2v[ht] + s0v;
            s1v = tb * w2v[ht] + s1v;
        }
        float s0 = (s0v[0] + s0v[1]) + (s0v[2] + s0v[3]);
        float s1 = (s1v[0] + s1v[1]) + (s1v[2] + s1v[3]);
        s0 += __shfl_xor(s0, 16, 64);
        s0 += __shfl_xor(s0, 32, 64);
        s1 += __shfl_xor(s1, 16, 64);
        s1 += __shfl_xor(s1, 32, 64);
        int k0 = c * 32 + n;
        s0 = (k0 <= q)      ? s0 + b2v : 0.f;
        s1 = (k0 + 16 <= q) ? s1 + b2v : 0.f;

        // scores -> A-frag via per-wave LDS strip (in-wave order)
        unsigned packed = (unsigned)f2bf(s0) | ((unsigned)f2bf(s1) << 16);
        if (quad == 0) strip[w][n] = packed;
        const unsigned* sp = &strip[w][(quad & 1) * 8];
        uint4 wv0 = *(const uint4*)sp;
        uint4 wv1 = *(const uint4*)(sp + 4);
        ix4 sw_;
        sw_[0] = (int)__builtin_amdgcn_perm(wv0.y, wv0.x, sel);
        sw_[1] = (int)__builtin_amdgcn_perm(wv0.w, wv0.z, sel);
        sw_[2] = (int)__builtin_amdgcn_perm(wv1.y, wv1.x, sel);
        sw_[3] = (int)__builtin_amdgcn_perm(wv1.w, wv1.z, sel);
        sx8 sfrag = __builtin_bit_cast(sx8, sw_);

        const unsigned short* le = (const unsigned short*)&bufE[p][0] + lane * 8;
        sx8 e0 = *(const sx8*)(le);
        sx8 e1 = *(const sx8*)(le + 512);
        sx8 e2 = *(const sx8*)(le + 1024);
        sx8 e3 = *(const sx8*)(le + 1536);

        eacc[0] = __builtin_amdgcn_mfma_f32_16x16x32_bf16(sfrag, e0, eacc[0], 0, 0, 0);
        eacc[1] = __builtin_amdgcn_mfma_f32_16x16x32_bf16(sfrag, e1, eacc[1], 0, 0, 0);
        eacc[2] = __builtin_amdgcn_mfma_f32_16x16x32_bf16(sfrag, e2, eacc[2], 0, 0, 0);
        eacc[3] = __builtin_amdgcn_mfma_f32_16x16x32_bf16(sfrag, e3, eacc[3], 0, 0, 0);

        // barrier: drains DMA (vmcnt) + protects buffer swap
        __syncthreads();
    }

    // all m-rows identical; lane's d = quad*16 + n = lane
    float ov = eacc[0][0];
    if (quad == 1) ov = eacc[1][0];
    if (quad == 2) ov = eacc[2][0];
    if (quad == 3) ov = eacc[3][0];
    out[bq * 64 + lane] = ov;
}

extern "C" void kernel_launch(void* const* d_in, const int* in_sizes, int n_in,
                              void* d_out, int out_size, void* d_ws, size_t ws_size,
                              hipStream_t stream) {
    const float* x   = (const float*)d_in[1];
    const float* vmk = (const float*)d_in[2];
    const float* W1  = (const float*)d_in[3];
    const float* b1  = (const float*)d_in[4];
    const float* pa  = (const float*)d_in[5];
    const float* W2  = (const float*)d_in[6];
    const float* b2  = (const float*)d_in[7];
    float* ws  = (float*)d_ws;
    float* out = (float*)d_out;

    hipLaunchKernelGGL(prep, dim3(NB * NN / 4), dim3(256), 0, stream,
                       x, vmk, W1, b1, ws);
    hipLaunchKernelGGL(k2_main, dim3(1024), dim3(256), 0, stream,
                       x, pa, W2, b2, ws, out);
}